// Round 1
// baseline (737.284 us; speedup 1.0000x reference)
//
#include <hip/hip_runtime.h>
#include <math.h>

#define NN 768
#define CC 1024
#define HCC 256
#define KK_TOP 20
#define NBR_K 21

// ---------------- generic tiled SGEMM: C = A(MxK) * B(KxN) (+bias) (+relu) ----------------
#define BM 64
#define BN 64
#define BK 16
__global__ __launch_bounds__(256) void sgemm_kernel(
    const float* __restrict__ A, const float* __restrict__ B,
    const float* __restrict__ bias, float* __restrict__ Cmat,
    int M, int Nn, int Kk, int lda, int ldb, int ldc, int relu_flag)
{
    __shared__ float As[BM][BK + 1];
    __shared__ float Bs[BK][BN + 1];
    int t = threadIdx.x;
    int tx = t & 15, ty = t >> 4;
    int row0 = blockIdx.y * BM, col0 = blockIdx.x * BN;
    float acc[4][4] = {};
    for (int k0 = 0; k0 < Kk; k0 += BK) {
#pragma unroll
        for (int e = 0; e < 4; e++) {
            int idx = t * 4 + e; int r = idx >> 4, c = idx & 15;
            int gr = row0 + r, gc = k0 + c;
            As[r][c] = (gr < M && gc < Kk) ? A[gr * lda + gc] : 0.f;
        }
#pragma unroll
        for (int e = 0; e < 4; e++) {
            int idx = t * 4 + e; int r = idx >> 6, c = idx & 63;
            int gr = k0 + r, gc = col0 + c;
            Bs[r][c] = (gr < Kk && gc < Nn) ? B[gr * ldb + gc] : 0.f;
        }
        __syncthreads();
#pragma unroll
        for (int kk = 0; kk < BK; kk++) {
            float a[4], b[4];
#pragma unroll
            for (int i = 0; i < 4; i++) a[i] = As[ty * 4 + i][kk];
#pragma unroll
            for (int j = 0; j < 4; j++) b[j] = Bs[kk][tx * 4 + j];
#pragma unroll
            for (int i = 0; i < 4; i++)
#pragma unroll
                for (int j = 0; j < 4; j++) acc[i][j] += a[i] * b[j];
        }
        __syncthreads();
    }
#pragma unroll
    for (int i = 0; i < 4; i++) {
        int gr = row0 + ty * 4 + i; if (gr >= M) continue;
#pragma unroll
        for (int j = 0; j < 4; j++) {
            int gc = col0 + tx * 4 + j; if (gc >= Nn) continue;
            float v = acc[i][j];
            if (bias) v += bias[gc];
            if (relu_flag) v = fmaxf(v, 0.f);
            Cmat[gr * ldc + gc] = v;
        }
    }
}

// ---------------- build x = [feats, boxes/800] (or reg_in = [h1, geom]) ----------------
__global__ void concat_kernel(const float* __restrict__ main_in, const float* __restrict__ boxes,
                              float* __restrict__ xbuf, int main_cols)
{
    int idx = blockIdx.x * 256 + threadIdx.x;
    int total = NN * (main_cols + 4);
    if (idx >= total) return;
    int cols = main_cols + 4;
    int n = idx / cols, c = idx % cols;
    float v;
    if (c < main_cols) v = main_in[n * main_cols + c];
    else v = boxes[n * 4 + (c - main_cols)] * (1.0f / 800.0f);
    xbuf[idx] = v;
}

// ---------------- fused rel[i,j] = sum_h relu(fa[i]+fb[j]+gdiff@Wg+b1)*W2 + b2 ----------------
__global__ __launch_bounds__(256) void rel_kernel(
    const float* __restrict__ fa, const float* __restrict__ fb,
    const float* __restrict__ boxes,
    const float* __restrict__ Wg,   // 4 x 256 (= W1 rows 2048..2051)
    const float* __restrict__ b1, const float* __restrict__ W2, const float* __restrict__ b2,
    float* __restrict__ rel)
{
    __shared__ float fas[16][257];
    __shared__ float fbs[16][257];
    __shared__ float wg_s[4][256];
    __shared__ float b1_s[256];
    __shared__ float w2_s[256];
    int t = threadIdx.x;
    int i0 = blockIdx.y * 16, j0 = blockIdx.x * 16;
    for (int e = t; e < 16 * 256; e += 256) {
        int r = e >> 8, c = e & 255;
        fas[r][c] = fa[(i0 + r) * 256 + c];
        fbs[r][c] = fb[(j0 + r) * 256 + c];
    }
    for (int e = t; e < 4 * 256; e += 256) wg_s[e >> 8][e & 255] = Wg[e];
    b1_s[t] = b1[t];
    w2_s[t] = W2[t];
    __syncthreads();
    int ti = t >> 4, tj = t & 15;
    int i = i0 + ti, j = j0 + tj;
    float bi0 = boxes[i * 4 + 0], bi1 = boxes[i * 4 + 1], bi2 = boxes[i * 4 + 2], bi3 = boxes[i * 4 + 3];
    float bj0 = boxes[j * 4 + 0], bj1 = boxes[j * 4 + 1], bj2 = boxes[j * 4 + 2], bj3 = boxes[j * 4 + 3];
    float g0 = fabsf(bi0 - bj0), g1 = fabsf(bi1 - bj1), g2 = fabsf(bi2 - bj2), g3 = fabsf(bi3 - bj3);
    float acc = 0.f;
#pragma unroll 4
    for (int h = 0; h < 256; h++) {
        float v = fas[ti][h] + fbs[tj][h] + b1_s[h]
                + g0 * wg_s[0][h] + g1 * wg_s[1][h] + g2 * wg_s[2][h] + g3 * wg_s[3][h];
        acc += fmaxf(v, 0.f) * w2_s[h];
    }
    acc += b2[0];
    if (i == j) acc = -1e9f;
    rel[i * NN + j] = acc;
}

// ---------------- top-20 per row (lowest-index tie-break), append self ----------------
__global__ __launch_bounds__(256) void topk_kernel(const float* __restrict__ rel, int* __restrict__ nbr)
{
    int i = blockIdx.x;
    __shared__ float vals[NN];
    __shared__ float vmax[256];
    __shared__ int vidx[256];
    int t = threadIdx.x;
    for (int e = t; e < NN; e += 256) vals[e] = rel[i * NN + e];
    __syncthreads();
    for (int kk = 0; kk < KK_TOP; kk++) {
        float best = -INFINITY; int bidx = NN;
        for (int e = t; e < NN; e += 256) {
            float v = vals[e];
            if (v > best) { best = v; bidx = e; }
        }
        vmax[t] = best; vidx[t] = bidx;
        __syncthreads();
        for (int s = 128; s > 0; s >>= 1) {
            if (t < s) {
                float v2 = vmax[t + s]; int i2 = vidx[t + s];
                if (v2 > vmax[t] || (v2 == vmax[t] && i2 < vidx[t])) { vmax[t] = v2; vidx[t] = i2; }
            }
            __syncthreads();
        }
        if (t == 0) { nbr[i * NBR_K + kk] = vidx[0]; vals[vidx[0]] = -INFINITY; }
        __syncthreads();
    }
    if (t == 0) nbr[i * NBR_K + KK_TOP] = i;
}

// ---------------- GAT1 attention coefficients: asrc/adst per (n,h) ----------------
__global__ void attn_coef_kernel(const float* __restrict__ xp,
                                 const float* __restrict__ g1as, const float* __restrict__ g1ad,
                                 float* __restrict__ asrc, float* __restrict__ adst)
{
    int idx = blockIdx.x * 256 + threadIdx.x;
    if (idx >= NN * 4) return;
    int n = idx >> 2, h = idx & 3;
    const float* xr = xp + n * 1024 + h * 256;
    const float* ws = g1as + h * 256;
    const float* wd = g1ad + h * 256;
    float s1 = 0.f, s2 = 0.f;
    for (int f = 0; f < 256; f++) { float v = xr[f]; s1 += v * ws[f]; s2 += v * wd[f]; }
    asrc[idx] = s1; adst[idx] = s2;
}

// ---------------- GAT1 aggregate: softmax over 21 nbrs, weighted sum, +bias, relu ----------------
__global__ __launch_bounds__(256) void gat1_kernel(
    const float* __restrict__ xp, const float* __restrict__ asrc, const float* __restrict__ adst,
    const int* __restrict__ nbr, const float* __restrict__ g1b, float* __restrict__ h1)
{
    int n = blockIdx.x; int t = threadIdx.x;
    __shared__ int nb[NBR_K];
    __shared__ float alpha[NBR_K][4];
    if (t < NBR_K) nb[t] = nbr[n * NBR_K + t];
    __syncthreads();
    if (t < NBR_K * 4) {
        int k = t % NBR_K, h = t / NBR_K;
        float e = asrc[nb[k] * 4 + h] + adst[n * 4 + h];
        e = (e > 0.f) ? e : 0.2f * e;
        alpha[k][h] = e;
    }
    __syncthreads();
    if (t < 4) {
        float m = -INFINITY;
        for (int k = 0; k < NBR_K; k++) m = fmaxf(m, alpha[k][t]);
        float s = 0.f;
        for (int k = 0; k < NBR_K; k++) { float ex = expf(alpha[k][t] - m); alpha[k][t] = ex; s += ex; }
        float inv = 1.f / s;
        for (int k = 0; k < NBR_K; k++) alpha[k][t] *= inv;
    }
    __syncthreads();
#pragma unroll
    for (int q = 0; q < 4; q++) {
        int c = q * 256 + t;
        int h = c >> 8;
        float acc = 0.f;
        for (int k = 0; k < NBR_K; k++) acc += alpha[k][h] * xp[nb[k] * 1024 + c];
        h1[n * 1024 + c] = fmaxf(acc + g1b[c], 0.f);
    }
}

// ---------------- GAT2 part A: xp2 = h1 @ g2W (1024x2), asrc2/adst2 ----------------
__global__ __launch_bounds__(256) void gat2a_kernel(
    const float* __restrict__ h1, const float* __restrict__ g2W,
    const float* __restrict__ g2as, const float* __restrict__ g2ad,
    float* __restrict__ xp2, float* __restrict__ aux2)
{
    int gid = blockIdx.x * blockDim.x + threadIdx.x;
    int wid = gid >> 6;
    int lane = threadIdx.x & 63;
    if (wid >= NN) return;
    float s0 = 0.f, s1 = 0.f;
    for (int k = lane; k < 1024; k += 64) {
        float v = h1[wid * 1024 + k];
        s0 += v * g2W[k * 2 + 0];
        s1 += v * g2W[k * 2 + 1];
    }
    for (int off = 32; off > 0; off >>= 1) { s0 += __shfl_down(s0, off); s1 += __shfl_down(s1, off); }
    if (lane == 0) {
        xp2[wid * 2 + 0] = s0; xp2[wid * 2 + 1] = s1;
        aux2[wid * 2 + 0] = s0 * g2as[0] + s1 * g2as[1];
        aux2[wid * 2 + 1] = s0 * g2ad[0] + s1 * g2ad[1];
    }
}

// ---------------- GAT2 part B: softmax over nbrs, output logits to out[:,0:2] ----------------
__global__ void gat2b_kernel(const float* __restrict__ xp2, const float* __restrict__ aux2,
                             const int* __restrict__ nbr, const float* __restrict__ g2b,
                             float* __restrict__ out)
{
    int n = blockIdx.x * 256 + threadIdx.x;
    if (n >= NN) return;
    float adst = aux2[n * 2 + 1];
    int nb[NBR_K];
    float e[NBR_K];
    float m = -INFINITY;
    for (int k = 0; k < NBR_K; k++) {
        nb[k] = nbr[n * NBR_K + k];
        float v = aux2[nb[k] * 2 + 0] + adst;
        v = (v > 0.f) ? v : 0.2f * v;
        e[k] = v; m = fmaxf(m, v);
    }
    float s = 0.f;
    for (int k = 0; k < NBR_K; k++) { e[k] = expf(e[k] - m); s += e[k]; }
    float inv = 1.f / s;
    float o0 = 0.f, o1 = 0.f;
    for (int k = 0; k < NBR_K; k++) {
        float a = e[k] * inv;
        o0 += a * xp2[nb[k] * 2 + 0];
        o1 += a * xp2[nb[k] * 2 + 1];
    }
    out[n * 6 + 0] = o0 + g2b[0];
    out[n * 6 + 1] = o1 + g2b[1];
}

// ---------------- delta = hid @ rW2 + rb2, box decode, out[:,2:6] ----------------
__global__ void decode_kernel(const float* __restrict__ hid, const float* __restrict__ rW2,
                              const float* __restrict__ rb2, const float* __restrict__ boxes,
                              float* __restrict__ out)
{
    int n = blockIdx.x * 256 + threadIdx.x;
    if (n >= NN) return;
    float d0 = 0.f, d1 = 0.f, d2 = 0.f, d3 = 0.f;
    for (int k = 0; k < 128; k++) {
        float v = hid[n * 128 + k];
        d0 += v * rW2[k * 4 + 0];
        d1 += v * rW2[k * 4 + 1];
        d2 += v * rW2[k * 4 + 2];
        d3 += v * rW2[k * 4 + 3];
    }
    d0 += rb2[0]; d1 += rb2[1]; d2 += rb2[2]; d3 += rb2[3];
    float x0 = boxes[n * 4 + 0], y0 = boxes[n * 4 + 1], x1 = boxes[n * 4 + 2], y1 = boxes[n * 4 + 3];
    float pw = x1 - x0, ph = y1 - y0;
    float pcx = x0 + 0.5f * pw, pcy = y0 + 0.5f * ph;
    float gcx = d0 * pw + pcx, gcy = d1 * ph + pcy;
    float gw = expf(d2) * pw, gh = expf(d3) * ph;
    out[n * 6 + 2] = gcx - 0.5f * gw;
    out[n * 6 + 3] = gcy - 0.5f * gh;
    out[n * 6 + 4] = gcx + 0.5f * gw;
    out[n * 6 + 5] = gcy + 0.5f * gh;
}

extern "C" void kernel_launch(void* const* d_in, const int* in_sizes, int n_in,
                              void* d_out, int out_size, void* d_ws, size_t ws_size,
                              hipStream_t stream)
{
    const float* feats = (const float*)d_in[0];
    const float* boxes = (const float*)d_in[1];
    const float* W1    = (const float*)d_in[2];
    const float* b1    = (const float*)d_in[3];
    const float* W2    = (const float*)d_in[4];
    const float* b2    = (const float*)d_in[5];
    const float* g1W   = (const float*)d_in[6];
    const float* g1as  = (const float*)d_in[7];
    const float* g1ad  = (const float*)d_in[8];
    const float* g1b   = (const float*)d_in[9];
    const float* g2W   = (const float*)d_in[10];
    const float* g2as  = (const float*)d_in[11];
    const float* g2ad  = (const float*)d_in[12];
    const float* g2b   = (const float*)d_in[13];
    const float* rW1   = (const float*)d_in[14];
    const float* rb1   = (const float*)d_in[15];
    const float* rW2   = (const float*)d_in[16];
    const float* rb2   = (const float*)d_in[17];
    float* out = (float*)d_out;

    // workspace layout (floats)
    float* ws = (float*)d_ws;
    float* fa   = ws;                  // 768*256
    float* fb   = fa   + 196608;       // 768*256
    float* rel  = fb   + 196608;       // 768*768
    float* xbuf = rel  + 589824;       // 768*1028  (also reused as reg_in)
    float* xp   = xbuf + 789504;       // 768*1024
    float* h1   = xp   + 786432;       // 768*1024
    float* asrc = h1   + 786432;       // 768*4
    float* adst = asrc + 3072;         // 768*4
    float* xp2  = adst + 3072;         // 768*2
    float* aux2 = xp2  + 1536;         // 768*2
    int*   nbr  = (int*)(aux2 + 1536); // 768*21 ints
    float* hid  = fa;                  // reuse fa (dead after rel): 768*128

    dim3 blk(256);

    // 1. xbuf = [feats, geom]
    concat_kernel<<<dim3((NN * 1028 + 255) / 256), blk, 0, stream>>>(feats, boxes, xbuf, 1024);

    // 2-3. fa = feats @ W1[:1024], fb = feats @ W1[1024:2048]
    sgemm_kernel<<<dim3(256 / BN, NN / BM), blk, 0, stream>>>(
        feats, W1, nullptr, fa, NN, 256, 1024, 1024, 256, 256, 0);
    sgemm_kernel<<<dim3(256 / BN, NN / BM), blk, 0, stream>>>(
        feats, W1 + 1024 * 256, nullptr, fb, NN, 256, 1024, 1024, 256, 256, 0);

    // 4. fused rel matrix (diag masked)
    rel_kernel<<<dim3(NN / 16, NN / 16), blk, 0, stream>>>(
        fa, fb, boxes, W1 + 2048 * 256, b1, W2, b2, rel);

    // 5. top-20 + self
    topk_kernel<<<dim3(NN), blk, 0, stream>>>(rel, nbr);

    // 6. xp = xbuf @ g1W   (768 x 1028 x 1024)
    sgemm_kernel<<<dim3(1024 / BN, NN / BM), blk, 0, stream>>>(
        xbuf, g1W, nullptr, xp, NN, 1024, 1028, 1028, 1024, 1024, 0);

    // 7. asrc/adst
    attn_coef_kernel<<<dim3((NN * 4 + 255) / 256), blk, 0, stream>>>(xp, g1as, g1ad, asrc, adst);

    // 8. GAT1 aggregate -> h1
    gat1_kernel<<<dim3(NN), blk, 0, stream>>>(xp, asrc, adst, nbr, g1b, h1);

    // 9. GAT2 projections
    gat2a_kernel<<<dim3(NN * 64 / 256), blk, 0, stream>>>(h1, g2W, g2as, g2ad, xp2, aux2);

    // 10. GAT2 aggregate -> out logits
    gat2b_kernel<<<dim3((NN + 255) / 256), blk, 0, stream>>>(xp2, aux2, nbr, g2b, out);

    // 11. reg_in = [h1, geom] (reuse xbuf)
    concat_kernel<<<dim3((NN * 1028 + 255) / 256), blk, 0, stream>>>(h1, boxes, xbuf, 1024);

    // 12. hid = relu(reg_in @ rW1 + rb1)   (768 x 1028 x 128)
    sgemm_kernel<<<dim3(128 / BN, NN / BM), blk, 0, stream>>>(
        xbuf, rW1, rb1, hid, NN, 128, 1028, 1028, 128, 128, 1);

    // 13. delta + box decode -> out boxes
    decode_kernel<<<dim3((NN + 255) / 256), blk, 0, stream>>>(hid, rW2, rb2, boxes, out);
}

// Round 2
// 284.066 us; speedup vs baseline: 2.5955x; 2.5955x over previous
//
#include <hip/hip_runtime.h>
#include <math.h>

#define NN 768
#define KK_TOP 20
#define NBR_K 21

// ================= split-K tiled SGEMM, 64x64 tile, 4x4 micro, b128 LDS =================
#define GBM 64
#define GBN 64
#define GBK 32
__global__ __launch_bounds__(256) void gemm_k(
    const float* __restrict__ A, const float* __restrict__ B,
    float* __restrict__ Cpart,
    int lda, int ldb, int ldc, int Kc, int half_off, int MN)
{
    __shared__ __align__(16) float As[GBK][GBM + 4];  // transposed: As[k][m]
    __shared__ __align__(16) float Bs[GBK][GBN + 4];
    int t = threadIdx.x;
    int row0 = blockIdx.y * GBM;
    int outcol0 = blockIdx.x * GBN;
    int col0 = outcol0;
    if (half_off) { int hh = col0 >> 8; B += (size_t)hh * half_off; col0 -= hh << 8; }
    int kz = blockIdx.z;
    const float* Ab = A + (size_t)row0 * lda + (size_t)kz * Kc;
    const float* Bb = B + (size_t)kz * Kc * ldb + col0;
    float* Cb = Cpart + (size_t)kz * MN + (size_t)row0 * ldc + outcol0;

    int kqa = t & 7, ma = t >> 3;   // A fill: k = kqa*4, rows ma and ma+32
    int nqb = t & 15, kb = t >> 4;  // B fill: n = nqb*4, k rows kb and kb+16

    float4 a0 = *(const float4*)(Ab + ma * lda + kqa * 4);
    float4 a1 = *(const float4*)(Ab + (ma + 32) * lda + kqa * 4);
    float4 b0 = *(const float4*)(Bb + kb * ldb + nqb * 4);
    float4 b1v = *(const float4*)(Bb + (kb + 16) * ldb + nqb * 4);

    int tx = t & 15, ty = t >> 4;
    float acc[4][4] = {};

    for (int k0 = 0; k0 < Kc; k0 += GBK) {
        As[kqa * 4 + 0][ma] = a0.x;
        As[kqa * 4 + 1][ma] = a0.y;
        As[kqa * 4 + 2][ma] = a0.z;
        As[kqa * 4 + 3][ma] = a0.w;
        As[kqa * 4 + 0][ma + 32] = a1.x;
        As[kqa * 4 + 1][ma + 32] = a1.y;
        As[kqa * 4 + 2][ma + 32] = a1.z;
        As[kqa * 4 + 3][ma + 32] = a1.w;
        *(float4*)&Bs[kb][nqb * 4] = b0;
        *(float4*)&Bs[kb + 16][nqb * 4] = b1v;
        __syncthreads();
        if (k0 + GBK < Kc) {
            a0 = *(const float4*)(Ab + ma * lda + k0 + GBK + kqa * 4);
            a1 = *(const float4*)(Ab + (ma + 32) * lda + k0 + GBK + kqa * 4);
            b0 = *(const float4*)(Bb + (size_t)(k0 + GBK + kb) * ldb + nqb * 4);
            b1v = *(const float4*)(Bb + (size_t)(k0 + GBK + kb + 16) * ldb + nqb * 4);
        }
#pragma unroll
        for (int kk = 0; kk < GBK; kk++) {
            float4 av = *(const float4*)&As[kk][ty * 4];
            float4 bv = *(const float4*)&Bs[kk][tx * 4];
            float a[4] = {av.x, av.y, av.z, av.w};
            float b[4] = {bv.x, bv.y, bv.z, bv.w};
#pragma unroll
            for (int i = 0; i < 4; i++)
#pragma unroll
                for (int j = 0; j < 4; j++) acc[i][j] += a[i] * b[j];
        }
        __syncthreads();
    }
#pragma unroll
    for (int i = 0; i < 4; i++) {
        float4 v = make_float4(acc[i][0], acc[i][1], acc[i][2], acc[i][3]);
        *(float4*)(Cb + (size_t)(ty * 4 + i) * ldc + tx * 4) = v;
    }
}

// ================= epilogue: sum 4 partials (fa|fb) =================
__global__ void ep_sum4(const float* __restrict__ p, float* __restrict__ out, int total4)
{
    int i = blockIdx.x * 256 + threadIdx.x;
    if (i >= total4) return;
    const float4* p4 = (const float4*)p;
    float4 a = p4[i], b = p4[i + total4], c = p4[i + 2 * total4], d = p4[i + 3 * total4];
    ((float4*)out)[i] = make_float4(a.x + b.x + c.x + d.x, a.y + b.y + c.y + d.y,
                                    a.z + b.z + c.z + d.z, a.w + b.w + c.w + d.w);
}

// ================= epilogue: xp = sum4 partials + geom rank-4 =================
__global__ void ep_xp(const float* __restrict__ p, const float* __restrict__ g1W,
                      const float* __restrict__ boxes, float* __restrict__ xp)
{
    int i = blockIdx.x * 256 + threadIdx.x;  // over 768*256 float4s
    int n = i >> 8, cq = i & 255;
    int c = cq * 4;
    const float4* p4 = (const float4*)p;
    const int s4 = NN * 1024 / 4;
    int base = n * 256 + cq;
    float4 s = p4[base];
    float4 s1 = p4[base + s4], s2 = p4[base + 2 * s4], s3 = p4[base + 3 * s4];
    s.x += s1.x + s2.x + s3.x; s.y += s1.y + s2.y + s3.y;
    s.z += s1.z + s2.z + s3.z; s.w += s1.w + s2.w + s3.w;
    const float inv = 1.0f / 800.0f;
    float g0 = boxes[n * 4 + 0] * inv, g1 = boxes[n * 4 + 1] * inv;
    float g2 = boxes[n * 4 + 2] * inv, g3 = boxes[n * 4 + 3] * inv;
    float4 w0 = *(const float4*)(g1W + (size_t)1024 * 1024 + c);
    float4 w1 = *(const float4*)(g1W + (size_t)1025 * 1024 + c);
    float4 w2 = *(const float4*)(g1W + (size_t)1026 * 1024 + c);
    float4 w3 = *(const float4*)(g1W + (size_t)1027 * 1024 + c);
    s.x += g0 * w0.x + g1 * w1.x + g2 * w2.x + g3 * w3.x;
    s.y += g0 * w0.y + g1 * w1.y + g2 * w2.y + g3 * w3.y;
    s.z += g0 * w0.z + g1 * w1.z + g2 * w2.z + g3 * w3.z;
    s.w += g0 * w0.w + g1 * w1.w + g2 * w2.w + g3 * w3.w;
    ((float4*)xp)[base] = s;
}

// ================= epilogue: hid = relu(sum8 partials + geom rank-4 + rb1) =================
__global__ void ep_hid(const float* __restrict__ p, const float* __restrict__ rW1,
                       const float* __restrict__ rb1, const float* __restrict__ boxes,
                       float* __restrict__ hid)
{
    int i = blockIdx.x * 256 + threadIdx.x;  // over 768*32 float4s
    if (i >= NN * 32) return;
    int n = i >> 5, cq = i & 31;
    int c = cq * 4;
    const float4* p4 = (const float4*)p;
    const int s4 = NN * 128 / 4;
    int base = n * 32 + cq;
    float sx = 0.f, sy = 0.f, sz = 0.f, sw = 0.f;
#pragma unroll
    for (int z = 0; z < 8; z++) {
        float4 v = p4[base + z * s4];
        sx += v.x; sy += v.y; sz += v.z; sw += v.w;
    }
    const float inv = 1.0f / 800.0f;
    float g0 = boxes[n * 4 + 0] * inv, g1 = boxes[n * 4 + 1] * inv;
    float g2 = boxes[n * 4 + 2] * inv, g3 = boxes[n * 4 + 3] * inv;
    float4 w0 = *(const float4*)(rW1 + 1024 * 128 + c);
    float4 w1 = *(const float4*)(rW1 + 1025 * 128 + c);
    float4 w2 = *(const float4*)(rW1 + 1026 * 128 + c);
    float4 w3 = *(const float4*)(rW1 + 1027 * 128 + c);
    float4 bb = *(const float4*)(rb1 + c);
    sx += g0 * w0.x + g1 * w1.x + g2 * w2.x + g3 * w3.x + bb.x;
    sy += g0 * w0.y + g1 * w1.y + g2 * w2.y + g3 * w3.y + bb.y;
    sz += g0 * w0.z + g1 * w1.z + g2 * w2.z + g3 * w3.z + bb.z;
    sw += g0 * w0.w + g1 * w1.w + g2 * w2.w + g3 * w3.w + bb.w;
    ((float4*)hid)[base] = make_float4(fmaxf(sx, 0.f), fmaxf(sy, 0.f), fmaxf(sz, 0.f), fmaxf(sw, 0.f));
}

// ================= fused rel[i,j] =================
__global__ __launch_bounds__(256) void rel_kernel(
    const float* __restrict__ fafb, const float* __restrict__ boxes,
    const float* __restrict__ Wg, const float* __restrict__ b1,
    const float* __restrict__ W2, const float* __restrict__ b2,
    float* __restrict__ rel)
{
    __shared__ __align__(16) float fas[16][260];
    __shared__ __align__(16) float fbs[16][260];
    __shared__ float4 wgt[256];
    __shared__ __align__(16) float w2s[256];
    int t = threadIdx.x;
    int i0 = blockIdx.y * 16, j0 = blockIdx.x * 16;
    for (int e = t; e < 1024; e += 256) {
        int r = e >> 6, cq = e & 63;
        float4 bb = *(const float4*)(b1 + cq * 4);
        float4 fv = *(const float4*)(fafb + (i0 + r) * 512 + cq * 4);
        float4 gv = *(const float4*)(fafb + (j0 + r) * 512 + 256 + cq * 4);
        *(float4*)&fas[r][cq * 4] = make_float4(fv.x + bb.x, fv.y + bb.y, fv.z + bb.z, fv.w + bb.w);
        *(float4*)&fbs[r][cq * 4] = gv;
    }
    wgt[t] = make_float4(Wg[t], Wg[256 + t], Wg[512 + t], Wg[768 + t]);
    w2s[t] = W2[t];
    __syncthreads();
    int ti = t >> 4, tj = t & 15;
    int i = i0 + ti, j = j0 + tj;
    float bi0 = boxes[i * 4 + 0], bi1 = boxes[i * 4 + 1], bi2 = boxes[i * 4 + 2], bi3 = boxes[i * 4 + 3];
    float bj0 = boxes[j * 4 + 0], bj1 = boxes[j * 4 + 1], bj2 = boxes[j * 4 + 2], bj3 = boxes[j * 4 + 3];
    float g0 = fabsf(bi0 - bj0), g1 = fabsf(bi1 - bj1), g2 = fabsf(bi2 - bj2), g3 = fabsf(bi3 - bj3);
    float acc = 0.f;
#pragma unroll 2
    for (int h = 0; h < 256; h += 4) {
        float4 a4 = *(const float4*)&fas[ti][h];
        float4 c4 = *(const float4*)&fbs[tj][h];
        float4 w2v = *(const float4*)&w2s[h];
        float4 q0 = wgt[h], q1 = wgt[h + 1], q2 = wgt[h + 2], q3 = wgt[h + 3];
        float v;
        v = a4.x + c4.x + g0 * q0.x + g1 * q0.y + g2 * q0.z + g3 * q0.w;
        acc += fmaxf(v, 0.f) * w2v.x;
        v = a4.y + c4.y + g0 * q1.x + g1 * q1.y + g2 * q1.z + g3 * q1.w;
        acc += fmaxf(v, 0.f) * w2v.y;
        v = a4.z + c4.z + g0 * q2.x + g1 * q2.y + g2 * q2.z + g3 * q2.w;
        acc += fmaxf(v, 0.f) * w2v.z;
        v = a4.w + c4.w + g0 * q3.x + g1 * q3.y + g2 * q3.z + g3 * q3.w;
        acc += fmaxf(v, 0.f) * w2v.w;
    }
    acc += b2[0];
    if (i == j) acc = -1e9f;
    rel[i * NN + j] = acc;
}

// ================= top-20 per row (lowest-index tie-break), append self =================
__global__ __launch_bounds__(256) void topk_kernel(const float* __restrict__ rel, int* __restrict__ nbr)
{
    int i = blockIdx.x;
    __shared__ float vals[NN];
    __shared__ float vmax[256];
    __shared__ int vidx[256];
    int t = threadIdx.x;
    for (int e = t; e < NN; e += 256) vals[e] = rel[i * NN + e];
    __syncthreads();
    for (int kk = 0; kk < KK_TOP; kk++) {
        float best = -INFINITY; int bidx = NN;
        for (int e = t; e < NN; e += 256) {
            float v = vals[e];
            if (v > best) { best = v; bidx = e; }
        }
        vmax[t] = best; vidx[t] = bidx;
        __syncthreads();
        for (int s = 128; s > 0; s >>= 1) {
            if (t < s) {
                float v2 = vmax[t + s]; int i2 = vidx[t + s];
                if (v2 > vmax[t] || (v2 == vmax[t] && i2 < vidx[t])) { vmax[t] = v2; vidx[t] = i2; }
            }
            __syncthreads();
        }
        if (t == 0) { nbr[i * NBR_K + kk] = vidx[0]; vals[vidx[0]] = -INFINITY; }
        __syncthreads();
    }
    if (t == 0) nbr[i * NBR_K + KK_TOP] = i;
}

// ================= GAT1 attention coefficients =================
__global__ void attn_coef_kernel(const float* __restrict__ xp,
                                 const float* __restrict__ g1as, const float* __restrict__ g1ad,
                                 float* __restrict__ asrc, float* __restrict__ adst)
{
    int idx = blockIdx.x * 256 + threadIdx.x;
    if (idx >= NN * 4) return;
    int n = idx >> 2, h = idx & 3;
    const float4* xr = (const float4*)(xp + (size_t)n * 1024 + h * 256);
    const float4* ws = (const float4*)(g1as + h * 256);
    const float4* wd = (const float4*)(g1ad + h * 256);
    float s1 = 0.f, s2 = 0.f;
    for (int f = 0; f < 64; f++) {
        float4 v = xr[f], a = ws[f], b = wd[f];
        s1 += v.x * a.x + v.y * a.y + v.z * a.z + v.w * a.w;
        s2 += v.x * b.x + v.y * b.y + v.z * b.z + v.w * b.w;
    }
    asrc[idx] = s1; adst[idx] = s2;
}

// ================= GAT1 aggregate =================
__global__ __launch_bounds__(256) void gat1_kernel(
    const float* __restrict__ xp, const float* __restrict__ asrc, const float* __restrict__ adst,
    const int* __restrict__ nbr, const float* __restrict__ g1b, float* __restrict__ h1)
{
    int n = blockIdx.x; int t = threadIdx.x;
    __shared__ int nb[NBR_K];
    __shared__ float alpha[NBR_K][4];
    if (t < NBR_K) nb[t] = nbr[n * NBR_K + t];
    __syncthreads();
    if (t < NBR_K * 4) {
        int k = t % NBR_K, h = t / NBR_K;
        float e = asrc[nb[k] * 4 + h] + adst[n * 4 + h];
        e = (e > 0.f) ? e : 0.2f * e;
        alpha[k][h] = e;
    }
    __syncthreads();
    if (t < 4) {
        float m = -INFINITY;
        for (int k = 0; k < NBR_K; k++) m = fmaxf(m, alpha[k][t]);
        float s = 0.f;
        for (int k = 0; k < NBR_K; k++) { float ex = expf(alpha[k][t] - m); alpha[k][t] = ex; s += ex; }
        float inv = 1.f / s;
        for (int k = 0; k < NBR_K; k++) alpha[k][t] *= inv;
    }
    __syncthreads();
#pragma unroll
    for (int q = 0; q < 4; q++) {
        int c = q * 256 + t;
        int h = c >> 8;
        float acc = 0.f;
        for (int k = 0; k < NBR_K; k++) acc += alpha[k][h] * xp[(size_t)nb[k] * 1024 + c];
        h1[(size_t)n * 1024 + c] = fmaxf(acc + g1b[c], 0.f);
    }
}

// ================= GAT2 part A =================
__global__ __launch_bounds__(256) void gat2a_kernel(
    const float* __restrict__ h1, const float* __restrict__ g2W,
    const float* __restrict__ g2as, const float* __restrict__ g2ad,
    float* __restrict__ xp2, float* __restrict__ aux2)
{
    int gid = blockIdx.x * blockDim.x + threadIdx.x;
    int wid = gid >> 6;
    int lane = threadIdx.x & 63;
    if (wid >= NN) return;
    float s0 = 0.f, s1 = 0.f;
    for (int k = lane; k < 1024; k += 64) {
        float v = h1[(size_t)wid * 1024 + k];
        s0 += v * g2W[k * 2 + 0];
        s1 += v * g2W[k * 2 + 1];
    }
    for (int off = 32; off > 0; off >>= 1) { s0 += __shfl_down(s0, off); s1 += __shfl_down(s1, off); }
    if (lane == 0) {
        xp2[wid * 2 + 0] = s0; xp2[wid * 2 + 1] = s1;
        aux2[wid * 2 + 0] = s0 * g2as[0] + s1 * g2as[1];
        aux2[wid * 2 + 1] = s0 * g2ad[0] + s1 * g2ad[1];
    }
}

// ================= GAT2 part B =================
__global__ void gat2b_kernel(const float* __restrict__ xp2, const float* __restrict__ aux2,
                             const int* __restrict__ nbr, const float* __restrict__ g2b,
                             float* __restrict__ out)
{
    int n = blockIdx.x * 256 + threadIdx.x;
    if (n >= NN) return;
    float adst = aux2[n * 2 + 1];
    int nb[NBR_K];
    float e[NBR_K];
    float m = -INFINITY;
    for (int k = 0; k < NBR_K; k++) {
        nb[k] = nbr[n * NBR_K + k];
        float v = aux2[nb[k] * 2 + 0] + adst;
        v = (v > 0.f) ? v : 0.2f * v;
        e[k] = v; m = fmaxf(m, v);
    }
    float s = 0.f;
    for (int k = 0; k < NBR_K; k++) { e[k] = expf(e[k] - m); s += e[k]; }
    float inv = 1.f / s;
    float o0 = 0.f, o1 = 0.f;
    for (int k = 0; k < NBR_K; k++) {
        float a = e[k] * inv;
        o0 += a * xp2[nb[k] * 2 + 0];
        o1 += a * xp2[nb[k] * 2 + 1];
    }
    out[n * 6 + 0] = o0 + g2b[0];
    out[n * 6 + 1] = o1 + g2b[1];
}

// ================= decode =================
__global__ void decode_kernel(const float* __restrict__ hid, const float* __restrict__ rW2,
                              const float* __restrict__ rb2, const float* __restrict__ boxes,
                              float* __restrict__ out)
{
    int n = blockIdx.x * 256 + threadIdx.x;
    if (n >= NN) return;
    float d0 = 0.f, d1 = 0.f, d2 = 0.f, d3 = 0.f;
    for (int k = 0; k < 128; k++) {
        float v = hid[n * 128 + k];
        d0 += v * rW2[k * 4 + 0];
        d1 += v * rW2[k * 4 + 1];
        d2 += v * rW2[k * 4 + 2];
        d3 += v * rW2[k * 4 + 3];
    }
    d0 += rb2[0]; d1 += rb2[1]; d2 += rb2[2]; d3 += rb2[3];
    float x0 = boxes[n * 4 + 0], y0 = boxes[n * 4 + 1], x1 = boxes[n * 4 + 2], y1 = boxes[n * 4 + 3];
    float pw = x1 - x0, ph = y1 - y0;
    float pcx = x0 + 0.5f * pw, pcy = y0 + 0.5f * ph;
    float gcx = d0 * pw + pcx, gcy = d1 * ph + pcy;
    float gw = expf(d2) * pw, gh = expf(d3) * ph;
    out[n * 6 + 2] = gcx - 0.5f * gw;
    out[n * 6 + 3] = gcy - 0.5f * gh;
    out[n * 6 + 4] = gcx + 0.5f * gw;
    out[n * 6 + 5] = gcy + 0.5f * gh;
}

extern "C" void kernel_launch(void* const* d_in, const int* in_sizes, int n_in,
                              void* d_out, int out_size, void* d_ws, size_t ws_size,
                              hipStream_t stream)
{
    const float* feats = (const float*)d_in[0];
    const float* boxes = (const float*)d_in[1];
    const float* W1    = (const float*)d_in[2];
    const float* b1    = (const float*)d_in[3];
    const float* W2    = (const float*)d_in[4];
    const float* b2    = (const float*)d_in[5];
    const float* g1W   = (const float*)d_in[6];
    const float* g1as  = (const float*)d_in[7];
    const float* g1ad  = (const float*)d_in[8];
    const float* g1b   = (const float*)d_in[9];
    const float* g2W   = (const float*)d_in[10];
    const float* g2as  = (const float*)d_in[11];
    const float* g2ad  = (const float*)d_in[12];
    const float* g2b   = (const float*)d_in[13];
    const float* rW1   = (const float*)d_in[14];
    const float* rb1   = (const float*)d_in[15];
    const float* rW2   = (const float*)d_in[16];
    const float* rb2   = (const float*)d_in[17];
    float* out = (float*)d_out;

    // workspace layout (floats)
    float* ws    = (float*)d_ws;
    float* arena = ws;                    // 4 * 768*1024 = 3,145,728 (split-K partials, reused)
    float* fafb  = arena + 3145728;       // 768*512
    float* xp    = fafb + 393216;         // 768*1024
    float* h1    = xp + 786432;           // 768*1024
    float* rel   = h1 + 786432;           // 768*768
    float* hid   = rel + 589824;          // 768*128
    float* asrc  = hid + 98304;           // 768*4
    float* adst  = asrc + 3072;           // 768*4
    float* xp2   = adst + 3072;           // 768*2
    float* aux2  = xp2 + 1536;            // 768*2
    int*   nbr   = (int*)(aux2 + 1536);   // 768*21

    dim3 blk(256);

    // G1: fa|fb = feats @ [Wa|Wb], split-K=4  -> arena partials
    gemm_k<<<dim3(8, 12, 4), blk, 0, stream>>>(
        feats, W1, arena, 1024, 256, 512, 256, 1024 * 256, NN * 512);
    ep_sum4<<<dim3(384), blk, 0, stream>>>(arena, fafb, NN * 512 / 4);

    // G2: xp = feats @ g1W[:1024], split-K=4; epilogue adds geom rank-4
    gemm_k<<<dim3(16, 12, 4), blk, 0, stream>>>(
        feats, g1W, arena, 1024, 1024, 1024, 256, 0, NN * 1024);
    ep_xp<<<dim3(768), blk, 0, stream>>>(arena, g1W, boxes, xp);

    // rel + topk
    rel_kernel<<<dim3(NN / 16, NN / 16), blk, 0, stream>>>(
        fafb, boxes, W1 + 2048 * 256, b1, W2, b2, rel);
    topk_kernel<<<dim3(NN), blk, 0, stream>>>(rel, nbr);

    // GAT1
    attn_coef_kernel<<<dim3(12), blk, 0, stream>>>(xp, g1as, g1ad, asrc, adst);
    gat1_kernel<<<dim3(NN), blk, 0, stream>>>(xp, asrc, adst, nbr, g1b, h1);

    // GAT2
    gat2a_kernel<<<dim3(NN * 64 / 256), blk, 0, stream>>>(h1, g2W, g2as, g2ad, xp2, aux2);
    gat2b_kernel<<<dim3((NN + 255) / 256), blk, 0, stream>>>(xp2, aux2, nbr, g2b, out);

    // G3: hid = relu(h1 @ rW1[:1024] + geom rank-4 + rb1), split-K=8
    gemm_k<<<dim3(2, 12, 8), blk, 0, stream>>>(
        h1, rW1, arena, 1024, 128, 128, 128, 0, NN * 128);
    ep_hid<<<dim3(96), blk, 0, stream>>>(arena, rW1, rb1, boxes, hid);

    // decode
    decode_kernel<<<dim3((NN + 255) / 256), blk, 0, stream>>>(hid, rW2, rb2, boxes, out);
}

// Round 3
// 247.896 us; speedup vs baseline: 2.9742x; 1.1459x over previous
//
#include <hip/hip_runtime.h>
#include <math.h>

#define NN 768
#define KK_TOP 20
#define NBR_K 21

// ================= split-K tiled SGEMM, 64x64 tile, 4x4 micro, b128 LDS =================
#define GBM 64
#define GBN 64
#define GBK 32
__global__ __launch_bounds__(256) void gemm_k(
    const float* __restrict__ A, const float* __restrict__ B,
    float* __restrict__ Cpart,
    int lda, int ldb, int ldc, int Kc, int half_off, int MN)
{
    __shared__ __align__(16) float As[GBK][GBM + 4];  // transposed: As[k][m]
    __shared__ __align__(16) float Bs[GBK][GBN + 4];
    int t = threadIdx.x;
    int row0 = blockIdx.y * GBM;
    int outcol0 = blockIdx.x * GBN;
    int col0 = outcol0;
    if (half_off) { int hh = col0 >> 8; B += (size_t)hh * half_off; col0 -= hh << 8; }
    int kz = blockIdx.z;
    const float* Ab = A + (size_t)row0 * lda + (size_t)kz * Kc;
    const float* Bb = B + (size_t)kz * Kc * ldb + col0;
    float* Cb = Cpart + (size_t)kz * MN + (size_t)row0 * ldc + outcol0;

    int kqa = t & 7, ma = t >> 3;   // A fill: k = kqa*4, rows ma and ma+32
    int nqb = t & 15, kb = t >> 4;  // B fill: n = nqb*4, k rows kb and kb+16

    float4 a0 = *(const float4*)(Ab + ma * lda + kqa * 4);
    float4 a1 = *(const float4*)(Ab + (ma + 32) * lda + kqa * 4);
    float4 b0 = *(const float4*)(Bb + kb * ldb + nqb * 4);
    float4 b1v = *(const float4*)(Bb + (kb + 16) * ldb + nqb * 4);

    int tx = t & 15, ty = t >> 4;
    float acc[4][4] = {};

    for (int k0 = 0; k0 < Kc; k0 += GBK) {
        As[kqa * 4 + 0][ma] = a0.x;
        As[kqa * 4 + 1][ma] = a0.y;
        As[kqa * 4 + 2][ma] = a0.z;
        As[kqa * 4 + 3][ma] = a0.w;
        As[kqa * 4 + 0][ma + 32] = a1.x;
        As[kqa * 4 + 1][ma + 32] = a1.y;
        As[kqa * 4 + 2][ma + 32] = a1.z;
        As[kqa * 4 + 3][ma + 32] = a1.w;
        *(float4*)&Bs[kb][nqb * 4] = b0;
        *(float4*)&Bs[kb + 16][nqb * 4] = b1v;
        __syncthreads();
        if (k0 + GBK < Kc) {
            a0 = *(const float4*)(Ab + ma * lda + k0 + GBK + kqa * 4);
            a1 = *(const float4*)(Ab + (ma + 32) * lda + k0 + GBK + kqa * 4);
            b0 = *(const float4*)(Bb + (size_t)(k0 + GBK + kb) * ldb + nqb * 4);
            b1v = *(const float4*)(Bb + (size_t)(k0 + GBK + kb + 16) * ldb + nqb * 4);
        }
#pragma unroll
        for (int kk = 0; kk < GBK; kk++) {
            float4 av = *(const float4*)&As[kk][ty * 4];
            float4 bv = *(const float4*)&Bs[kk][tx * 4];
            float a[4] = {av.x, av.y, av.z, av.w};
            float b[4] = {bv.x, bv.y, bv.z, bv.w};
#pragma unroll
            for (int i = 0; i < 4; i++)
#pragma unroll
                for (int j = 0; j < 4; j++) acc[i][j] += a[i] * b[j];
        }
        __syncthreads();
    }
#pragma unroll
    for (int i = 0; i < 4; i++) {
        float4 v = make_float4(acc[i][0], acc[i][1], acc[i][2], acc[i][3]);
        *(float4*)(Cb + (size_t)(ty * 4 + i) * ldc + tx * 4) = v;
    }
}

// ================= epilogue: sum 4 partials (fa|fb) =================
__global__ void ep_sum4(const float* __restrict__ p, float* __restrict__ out, int total4)
{
    int i = blockIdx.x * 256 + threadIdx.x;
    if (i >= total4) return;
    const float4* p4 = (const float4*)p;
    float4 a = p4[i], b = p4[i + total4], c = p4[i + 2 * total4], d = p4[i + 3 * total4];
    ((float4*)out)[i] = make_float4(a.x + b.x + c.x + d.x, a.y + b.y + c.y + d.y,
                                    a.z + b.z + c.z + d.z, a.w + b.w + c.w + d.w);
}

// ================= epilogue: xp = sum4 partials + geom rank-4 =================
__global__ void ep_xp(const float* __restrict__ p, const float* __restrict__ g1W,
                      const float* __restrict__ boxes, float* __restrict__ xp)
{
    int i = blockIdx.x * 256 + threadIdx.x;  // over 768*256 float4s
    int n = i >> 8, cq = i & 255;
    int c = cq * 4;
    const float4* p4 = (const float4*)p;
    const int s4 = NN * 1024 / 4;
    int base = n * 256 + cq;
    float4 s = p4[base];
    float4 s1 = p4[base + s4], s2 = p4[base + 2 * s4], s3 = p4[base + 3 * s4];
    s.x += s1.x + s2.x + s3.x; s.y += s1.y + s2.y + s3.y;
    s.z += s1.z + s2.z + s3.z; s.w += s1.w + s2.w + s3.w;
    const float inv = 1.0f / 800.0f;
    float g0 = boxes[n * 4 + 0] * inv, g1 = boxes[n * 4 + 1] * inv;
    float g2 = boxes[n * 4 + 2] * inv, g3 = boxes[n * 4 + 3] * inv;
    float4 w0 = *(const float4*)(g1W + (size_t)1024 * 1024 + c);
    float4 w1 = *(const float4*)(g1W + (size_t)1025 * 1024 + c);
    float4 w2 = *(const float4*)(g1W + (size_t)1026 * 1024 + c);
    float4 w3 = *(const float4*)(g1W + (size_t)1027 * 1024 + c);
    s.x += g0 * w0.x + g1 * w1.x + g2 * w2.x + g3 * w3.x;
    s.y += g0 * w0.y + g1 * w1.y + g2 * w2.y + g3 * w3.y;
    s.z += g0 * w0.z + g1 * w1.z + g2 * w2.z + g3 * w3.z;
    s.w += g0 * w0.w + g1 * w1.w + g2 * w2.w + g3 * w3.w;
    ((float4*)xp)[base] = s;
}

// ================= epilogue: hid = relu(sum8 partials + geom rank-4 + rb1) =================
__global__ void ep_hid(const float* __restrict__ p, const float* __restrict__ rW1,
                       const float* __restrict__ rb1, const float* __restrict__ boxes,
                       float* __restrict__ hid)
{
    int i = blockIdx.x * 256 + threadIdx.x;  // over 768*32 float4s
    if (i >= NN * 32) return;
    int n = i >> 5, cq = i & 31;
    int c = cq * 4;
    const float4* p4 = (const float4*)p;
    const int s4 = NN * 128 / 4;
    int base = n * 32 + cq;
    float sx = 0.f, sy = 0.f, sz = 0.f, sw = 0.f;
#pragma unroll
    for (int z = 0; z < 8; z++) {
        float4 v = p4[base + z * s4];
        sx += v.x; sy += v.y; sz += v.z; sw += v.w;
    }
    const float inv = 1.0f / 800.0f;
    float g0 = boxes[n * 4 + 0] * inv, g1 = boxes[n * 4 + 1] * inv;
    float g2 = boxes[n * 4 + 2] * inv, g3 = boxes[n * 4 + 3] * inv;
    float4 w0 = *(const float4*)(rW1 + 1024 * 128 + c);
    float4 w1 = *(const float4*)(rW1 + 1025 * 128 + c);
    float4 w2 = *(const float4*)(rW1 + 1026 * 128 + c);
    float4 w3 = *(const float4*)(rW1 + 1027 * 128 + c);
    float4 bb = *(const float4*)(rb1 + c);
    sx += g0 * w0.x + g1 * w1.x + g2 * w2.x + g3 * w3.x + bb.x;
    sy += g0 * w0.y + g1 * w1.y + g2 * w2.y + g3 * w3.y + bb.y;
    sz += g0 * w0.z + g1 * w1.z + g2 * w2.z + g3 * w3.z + bb.z;
    sw += g0 * w0.w + g1 * w1.w + g2 * w2.w + g3 * w3.w + bb.w;
    ((float4*)hid)[base] = make_float4(fmaxf(sx, 0.f), fmaxf(sy, 0.f), fmaxf(sz, 0.f), fmaxf(sw, 0.f));
}

// ================= pack: wgt4[h]={Wg[0..3][h]}, w2p[h]; consts=[Cw0..Cw3, bw] =================
__global__ void pack_kernel(const float* __restrict__ W1, const float* __restrict__ W2,
                            const float* __restrict__ b1,
                            float4* __restrict__ wgt4, float* __restrict__ w2p,
                            float* __restrict__ consts)
{
    int t = threadIdx.x;  // 0..255
    const float* Wg = W1 + 2048 * 256;
    float q0 = Wg[t], q1 = Wg[256 + t], q2 = Wg[512 + t], q3 = Wg[768 + t];
    float w2 = W2[t];
    wgt4[t] = make_float4(q0, q1, q2, q3);
    w2p[t] = w2;
    __shared__ float red[256];
    float vals[5] = {q0 * w2, q1 * w2, q2 * w2, q3 * w2, b1[t] * w2};
    for (int d = 0; d < 5; d++) {
        red[t] = vals[d]; __syncthreads();
        for (int s = 128; s > 0; s >>= 1) {
            if (t < s) red[t] += red[t + s];
            __syncthreads();
        }
        if (t == 0) consts[d] = red[0];
        __syncthreads();
    }
}

// ================= rowdot: Arow[i]=fa[i]·w2, Brow[i]=fb[i]·w2 (one wave per row) =============
__global__ __launch_bounds__(256) void rowdot_kernel(
    const float* __restrict__ fafb, const float* __restrict__ w2p,
    float* __restrict__ Arow, float* __restrict__ Brow)
{
    int gid = blockIdx.x * 256 + threadIdx.x;
    int row = gid >> 6;
    int lane = gid & 63;
    const float4* fr = (const float4*)(fafb + (size_t)row * 512);
    float4 w = ((const float4*)w2p)[lane];
    float4 v1 = fr[lane], v2 = fr[64 + lane];
    float s1 = v1.x * w.x + v1.y * w.y + v1.z * w.z + v1.w * w.w;
    float s2 = v2.x * w.x + v2.y * w.y + v2.z * w.z + v2.w * w.w;
#pragma unroll
    for (int off = 32; off > 0; off >>= 1) {
        s1 += __shfl_xor(s1, off);
        s2 += __shfl_xor(s2, off);
    }
    if (lane == 0) { Arow[row] = s1; Brow[row] = s2; }
}

// ================= fused rel, v2: abs-trick + 2x2/thread + scalar uniform coefs ============
#define REL_ACC(FA0, FA1, FB0, FB1, Q, W)                                           \
    {                                                                               \
        float v;                                                                    \
        v = FA0 + FB0;                                                              \
        v = fmaf(g00.x, Q.x, v); v = fmaf(g00.y, Q.y, v);                           \
        v = fmaf(g00.z, Q.z, v); v = fmaf(g00.w, Q.w, v);                           \
        acc00 = fmaf(fabsf(v), W, acc00);                                           \
        v = FA0 + FB1;                                                              \
        v = fmaf(g01.x, Q.x, v); v = fmaf(g01.y, Q.y, v);                           \
        v = fmaf(g01.z, Q.z, v); v = fmaf(g01.w, Q.w, v);                           \
        acc01 = fmaf(fabsf(v), W, acc01);                                           \
        v = FA1 + FB0;                                                              \
        v = fmaf(g10.x, Q.x, v); v = fmaf(g10.y, Q.y, v);                           \
        v = fmaf(g10.z, Q.z, v); v = fmaf(g10.w, Q.w, v);                           \
        acc10 = fmaf(fabsf(v), W, acc10);                                           \
        v = FA1 + FB1;                                                              \
        v = fmaf(g11.x, Q.x, v); v = fmaf(g11.y, Q.y, v);                           \
        v = fmaf(g11.z, Q.z, v); v = fmaf(g11.w, Q.w, v);                           \
        acc11 = fmaf(fabsf(v), W, acc11);                                           \
    }

__global__ __launch_bounds__(256) void rel_kernel(
    const float* __restrict__ fafb, const float* __restrict__ boxes,
    const float4* __restrict__ wgt4, const float* __restrict__ w2p,
    const float* __restrict__ consts, const float* __restrict__ b1,
    const float* __restrict__ Arow, const float* __restrict__ Brow,
    const float* __restrict__ b2, float* __restrict__ rel)
{
    __shared__ __align__(16) float fas[32][132];  // fa + b1, phase-local 128 h
    __shared__ __align__(16) float fbs[32][132];
    int t = threadIdx.x;
    int tx = t & 15, ty = t >> 4;
    int i0 = blockIdx.y * 32, j0 = blockIdx.x * 32;
    int ia = i0 + ty, ib = i0 + ty + 16;
    int ja = j0 + tx, jb = j0 + tx + 16;

    float4 Bi0 = *(const float4*)(boxes + ia * 4);
    float4 Bi1 = *(const float4*)(boxes + ib * 4);
    float4 Bj0 = *(const float4*)(boxes + ja * 4);
    float4 Bj1 = *(const float4*)(boxes + jb * 4);
    float4 g00 = make_float4(fabsf(Bi0.x - Bj0.x), fabsf(Bi0.y - Bj0.y), fabsf(Bi0.z - Bj0.z), fabsf(Bi0.w - Bj0.w));
    float4 g01 = make_float4(fabsf(Bi0.x - Bj1.x), fabsf(Bi0.y - Bj1.y), fabsf(Bi0.z - Bj1.z), fabsf(Bi0.w - Bj1.w));
    float4 g10 = make_float4(fabsf(Bi1.x - Bj0.x), fabsf(Bi1.y - Bj0.y), fabsf(Bi1.z - Bj0.z), fabsf(Bi1.w - Bj0.w));
    float4 g11 = make_float4(fabsf(Bi1.x - Bj1.x), fabsf(Bi1.y - Bj1.y), fabsf(Bi1.z - Bj1.z), fabsf(Bi1.w - Bj1.w));

    float acc00 = 0.f, acc01 = 0.f, acc10 = 0.f, acc11 = 0.f;

    for (int p = 0; p < 2; p++) {
        for (int e = t; e < 1024; e += 256) {
            int r = e >> 5, cq = e & 31;
            float4 bb = *(const float4*)(b1 + p * 128 + cq * 4);
            float4 fv = *(const float4*)(fafb + (size_t)(i0 + r) * 512 + p * 128 + cq * 4);
            float4 gv = *(const float4*)(fafb + (size_t)(j0 + r) * 512 + 256 + p * 128 + cq * 4);
            *(float4*)&fas[r][cq * 4] = make_float4(fv.x + bb.x, fv.y + bb.y, fv.z + bb.z, fv.w + bb.w);
            *(float4*)&fbs[r][cq * 4] = gv;
        }
        __syncthreads();
        const float4* wg = wgt4 + p * 128;
        const float* w2 = w2p + p * 128;
#pragma unroll 8
        for (int hc = 0; hc < 32; hc++) {
            int h4 = hc * 4;
            float4 fa0 = *(const float4*)&fas[ty][h4];
            float4 fa1 = *(const float4*)&fas[ty + 16][h4];
            float4 fb0 = *(const float4*)&fbs[tx][h4];
            float4 fb1 = *(const float4*)&fbs[tx + 16][h4];
            float4 w2v = *(const float4*)(w2 + h4);
            float4 q0 = wg[h4], q1 = wg[h4 + 1], q2 = wg[h4 + 2], q3 = wg[h4 + 3];
            REL_ACC(fa0.x, fa1.x, fb0.x, fb1.x, q0, w2v.x);
            REL_ACC(fa0.y, fa1.y, fb0.y, fb1.y, q1, w2v.y);
            REL_ACC(fa0.z, fa1.z, fb0.z, fb1.z, q2, w2v.z);
            REL_ACC(fa0.w, fa1.w, fb0.w, fb1.w, q3, w2v.w);
        }
        __syncthreads();
    }

    float c0 = consts[0], c1 = consts[1], c2 = consts[2], c3 = consts[3], c4 = consts[4];
    float b2v = b2[0];
    float Ai0 = Arow[ia], Ai1 = Arow[ib];
    float Bja = Brow[ja], Bjb = Brow[jb];

    float lin, r00, r01, r10, r11;
    lin = Ai0 + Bja + g00.x * c0 + g00.y * c1 + g00.z * c2 + g00.w * c3 + c4;
    r00 = 0.5f * (lin + acc00) + b2v;
    lin = Ai0 + Bjb + g01.x * c0 + g01.y * c1 + g01.z * c2 + g01.w * c3 + c4;
    r01 = 0.5f * (lin + acc01) + b2v;
    lin = Ai1 + Bja + g10.x * c0 + g10.y * c1 + g10.z * c2 + g10.w * c3 + c4;
    r10 = 0.5f * (lin + acc10) + b2v;
    lin = Ai1 + Bjb + g11.x * c0 + g11.y * c1 + g11.z * c2 + g11.w * c3 + c4;
    r11 = 0.5f * (lin + acc11) + b2v;
    rel[(size_t)ia * NN + ja] = (ia == ja) ? -1e9f : r00;
    rel[(size_t)ia * NN + jb] = (ia == jb) ? -1e9f : r01;
    rel[(size_t)ib * NN + ja] = (ib == ja) ? -1e9f : r10;
    rel[(size_t)ib * NN + jb] = (ib == jb) ? -1e9f : r11;
}

// ================= top-20 per row: one wave per row, register-resident =================
__global__ __launch_bounds__(256) void topk_kernel(const float* __restrict__ rel, int* __restrict__ nbr)
{
    int gid = blockIdx.x * 256 + threadIdx.x;
    int row = gid >> 6;
    int lane = gid & 63;
    const float* rp = rel + (size_t)row * NN;
    float v[12];
#pragma unroll
    for (int q = 0; q < 12; q++) v[q] = rp[q * 64 + lane];
    for (int kk = 0; kk < KK_TOP; kk++) {
        float best = v[0]; int bq = 0;
#pragma unroll
        for (int q = 1; q < 12; q++) {
            if (v[q] > best) { best = v[q]; bq = q; }
        }
        int bidx = bq * 64 + lane;
#pragma unroll
        for (int off = 32; off > 0; off >>= 1) {
            float ov = __shfl_xor(best, off);
            int oi = __shfl_xor(bidx, off);
            if (ov > best || (ov == best && oi < bidx)) { best = ov; bidx = oi; }
        }
        if (lane == 0) nbr[row * NBR_K + kk] = bidx;
        int bl = bidx & 63, bq2 = bidx >> 6;
        if (lane == bl) {
#pragma unroll
            for (int q = 0; q < 12; q++)
                if (q == bq2) v[q] = -INFINITY;
        }
    }
    if (lane == 0) nbr[row * NBR_K + KK_TOP] = row;
}

// ================= GAT1 attention coefficients: one wave per (n,h) =================
__global__ __launch_bounds__(256) void attn_coef_kernel(
    const float* __restrict__ xp, const float* __restrict__ g1as, const float* __restrict__ g1ad,
    float* __restrict__ asrc, float* __restrict__ adst)
{
    int gid = blockIdx.x * 256 + threadIdx.x;
    int wv = gid >> 6;   // (n,h) pair, 0..3071
    int lane = gid & 63;
    int n = wv >> 2, h = wv & 3;
    const float4* xr = (const float4*)(xp + (size_t)n * 1024 + h * 256);
    const float4* wsrc = (const float4*)(g1as + h * 256);
    const float4* wdst = (const float4*)(g1ad + h * 256);
    float4 x4 = xr[lane], a4 = wsrc[lane], b4 = wdst[lane];
    float s1 = x4.x * a4.x + x4.y * a4.y + x4.z * a4.z + x4.w * a4.w;
    float s2 = x4.x * b4.x + x4.y * b4.y + x4.z * b4.z + x4.w * b4.w;
#pragma unroll
    for (int off = 32; off > 0; off >>= 1) {
        s1 += __shfl_xor(s1, off);
        s2 += __shfl_xor(s2, off);
    }
    if (lane == 0) { asrc[wv] = s1; adst[wv] = s2; }
}

// ================= GAT1 aggregate =================
__global__ __launch_bounds__(256) void gat1_kernel(
    const float* __restrict__ xp, const float* __restrict__ asrc, const float* __restrict__ adst,
    const int* __restrict__ nbr, const float* __restrict__ g1b, float* __restrict__ h1)
{
    int n = blockIdx.x; int t = threadIdx.x;
    __shared__ int nb[NBR_K];
    __shared__ float alpha[NBR_K][4];
    if (t < NBR_K) nb[t] = nbr[n * NBR_K + t];
    __syncthreads();
    if (t < NBR_K * 4) {
        int k = t % NBR_K, h = t / NBR_K;
        float e = asrc[nb[k] * 4 + h] + adst[n * 4 + h];
        e = (e > 0.f) ? e : 0.2f * e;
        alpha[k][h] = e;
    }
    __syncthreads();
    if (t < 4) {
        float m = -INFINITY;
        for (int k = 0; k < NBR_K; k++) m = fmaxf(m, alpha[k][t]);
        float s = 0.f;
        for (int k = 0; k < NBR_K; k++) { float ex = expf(alpha[k][t] - m); alpha[k][t] = ex; s += ex; }
        float inv = 1.f / s;
        for (int k = 0; k < NBR_K; k++) alpha[k][t] *= inv;
    }
    __syncthreads();
#pragma unroll
    for (int q = 0; q < 4; q++) {
        int c = q * 256 + t;
        int h = c >> 8;
        float acc = 0.f;
        for (int k = 0; k < NBR_K; k++) acc += alpha[k][h] * xp[(size_t)nb[k] * 1024 + c];
        h1[(size_t)n * 1024 + c] = fmaxf(acc + g1b[c], 0.f);
    }
}

// ================= GAT2 part A =================
__global__ __launch_bounds__(256) void gat2a_kernel(
    const float* __restrict__ h1, const float* __restrict__ g2W,
    const float* __restrict__ g2as, const float* __restrict__ g2ad,
    float* __restrict__ xp2, float* __restrict__ aux2)
{
    int gid = blockIdx.x * blockDim.x + threadIdx.x;
    int wid = gid >> 6;
    int lane = threadIdx.x & 63;
    if (wid >= NN) return;
    float s0 = 0.f, s1 = 0.f;
    for (int k = lane; k < 1024; k += 64) {
        float v = h1[(size_t)wid * 1024 + k];
        s0 += v * g2W[k * 2 + 0];
        s1 += v * g2W[k * 2 + 1];
    }
    for (int off = 32; off > 0; off >>= 1) { s0 += __shfl_down(s0, off); s1 += __shfl_down(s1, off); }
    if (lane == 0) {
        xp2[wid * 2 + 0] = s0; xp2[wid * 2 + 1] = s1;
        aux2[wid * 2 + 0] = s0 * g2as[0] + s1 * g2as[1];
        aux2[wid * 2 + 1] = s0 * g2ad[0] + s1 * g2ad[1];
    }
}

// ================= GAT2 part B =================
__global__ void gat2b_kernel(const float* __restrict__ xp2, const float* __restrict__ aux2,
                             const int* __restrict__ nbr, const float* __restrict__ g2b,
                             float* __restrict__ out)
{
    int n = blockIdx.x * 256 + threadIdx.x;
    if (n >= NN) return;
    float adst = aux2[n * 2 + 1];
    int nb[NBR_K];
    float e[NBR_K];
    float m = -INFINITY;
    for (int k = 0; k < NBR_K; k++) {
        nb[k] = nbr[n * NBR_K + k];
        float v = aux2[nb[k] * 2 + 0] + adst;
        v = (v > 0.f) ? v : 0.2f * v;
        e[k] = v; m = fmaxf(m, v);
    }
    float s = 0.f;
    for (int k = 0; k < NBR_K; k++) { e[k] = expf(e[k] - m); s += e[k]; }
    float inv = 1.f / s;
    float o0 = 0.f, o1 = 0.f;
    for (int k = 0; k < NBR_K; k++) {
        float a = e[k] * inv;
        o0 += a * xp2[nb[k] * 2 + 0];
        o1 += a * xp2[nb[k] * 2 + 1];
    }
    out[n * 6 + 0] = o0 + g2b[0];
    out[n * 6 + 1] = o1 + g2b[1];
}

// ================= decode =================
__global__ void decode_kernel(const float* __restrict__ hid, const float* __restrict__ rW2,
                              const float* __restrict__ rb2, const float* __restrict__ boxes,
                              float* __restrict__ out)
{
    int n = blockIdx.x * 256 + threadIdx.x;
    if (n >= NN) return;
    float d0 = 0.f, d1 = 0.f, d2 = 0.f, d3 = 0.f;
    for (int k = 0; k < 128; k++) {
        float v = hid[n * 128 + k];
        d0 += v * rW2[k * 4 + 0];
        d1 += v * rW2[k * 4 + 1];
        d2 += v * rW2[k * 4 + 2];
        d3 += v * rW2[k * 4 + 3];
    }
    d0 += rb2[0]; d1 += rb2[1]; d2 += rb2[2]; d3 += rb2[3];
    float x0 = boxes[n * 4 + 0], y0 = boxes[n * 4 + 1], x1 = boxes[n * 4 + 2], y1 = boxes[n * 4 + 3];
    float pw = x1 - x0, ph = y1 - y0;
    float pcx = x0 + 0.5f * pw, pcy = y0 + 0.5f * ph;
    float gcx = d0 * pw + pcx, gcy = d1 * ph + pcy;
    float gw = expf(d2) * pw, gh = expf(d3) * ph;
    out[n * 6 + 2] = gcx - 0.5f * gw;
    out[n * 6 + 3] = gcy - 0.5f * gh;
    out[n * 6 + 4] = gcx + 0.5f * gw;
    out[n * 6 + 5] = gcy + 0.5f * gh;
}

extern "C" void kernel_launch(void* const* d_in, const int* in_sizes, int n_in,
                              void* d_out, int out_size, void* d_ws, size_t ws_size,
                              hipStream_t stream)
{
    const float* feats = (const float*)d_in[0];
    const float* boxes = (const float*)d_in[1];
    const float* W1    = (const float*)d_in[2];
    const float* b1    = (const float*)d_in[3];
    const float* W2    = (const float*)d_in[4];
    const float* b2    = (const float*)d_in[5];
    const float* g1W   = (const float*)d_in[6];
    const float* g1as  = (const float*)d_in[7];
    const float* g1ad  = (const float*)d_in[8];
    const float* g1b   = (const float*)d_in[9];
    const float* g2W   = (const float*)d_in[10];
    const float* g2as  = (const float*)d_in[11];
    const float* g2ad  = (const float*)d_in[12];
    const float* g2b   = (const float*)d_in[13];
    const float* rW1   = (const float*)d_in[14];
    const float* rb1   = (const float*)d_in[15];
    const float* rW2   = (const float*)d_in[16];
    const float* rb2   = (const float*)d_in[17];
    float* out = (float*)d_out;

    // workspace layout (floats)
    float* ws    = (float*)d_ws;
    float* arena = ws;                    // 4 * 768*1024 (split-K partials, reused)
    float* fafb  = arena + 3145728;       // 768*512
    float* xp    = fafb + 393216;         // 768*1024
    float* h1    = xp + 786432;           // 768*1024
    float* rel   = h1 + 786432;           // 768*768
    float* hid   = rel + 589824;          // 768*128
    float* asrc  = hid + 98304;           // 768*4
    float* adst  = asrc + 3072;           // 768*4
    float* xp2   = adst + 3072;           // 768*2
    float* aux2  = xp2 + 1536;            // 768*2
    float4* wgt4 = (float4*)(aux2 + 1536);// 256 float4 (16B aligned: offset %4==0 floats)
    float* w2p   = (float*)(wgt4 + 256);  // 256
    float* consts= w2p + 256;             // 8
    float* Arow  = consts + 8;            // 768
    float* Brow  = Arow + 768;            // 768
    int*   nbr   = (int*)(Brow + 768);    // 768*21

    dim3 blk(256);

    // G1: fa|fb = feats @ [Wa|Wb], split-K=4 -> arena partials -> fafb
    gemm_k<<<dim3(8, 12, 4), blk, 0, stream>>>(
        feats, W1, arena, 1024, 256, 512, 256, 1024 * 256, NN * 512);
    ep_sum4<<<dim3(384), blk, 0, stream>>>(arena, fafb, NN * 512 / 4);

    // pack coefficients + row dots for rel closed form
    pack_kernel<<<dim3(1), blk, 0, stream>>>(W1, W2, b1, wgt4, w2p, consts);
    rowdot_kernel<<<dim3(192), blk, 0, stream>>>(fafb, w2p, Arow, Brow);

    // G2: xp = feats @ g1W[:1024], split-K=4; epilogue adds geom rank-4
    gemm_k<<<dim3(16, 12, 4), blk, 0, stream>>>(
        feats, g1W, arena, 1024, 1024, 1024, 256, 0, NN * 1024);
    ep_xp<<<dim3(768), blk, 0, stream>>>(arena, g1W, boxes, xp);

    // rel + topk
    rel_kernel<<<dim3(NN / 32, NN / 32), blk, 0, stream>>>(
        fafb, boxes, wgt4, w2p, consts, b1, Arow, Brow, b2, rel);
    topk_kernel<<<dim3(192), blk, 0, stream>>>(rel, nbr);

    // GAT1
    attn_coef_kernel<<<dim3(768), blk, 0, stream>>>(xp, g1as, g1ad, asrc, adst);
    gat1_kernel<<<dim3(NN), blk, 0, stream>>>(xp, asrc, adst, nbr, g1b, h1);

    // GAT2
    gat2a_kernel<<<dim3(NN * 64 / 256), blk, 0, stream>>>(h1, g2W, g2as, g2ad, xp2, aux2);
    gat2b_kernel<<<dim3((NN + 255) / 256), blk, 0, stream>>>(xp2, aux2, nbr, g2b, out);

    // G3: hid = relu(h1 @ rW1[:1024] + geom rank-4 + rb1), split-K=8
    gemm_k<<<dim3(2, 12, 8), blk, 0, stream>>>(
        h1, rW1, arena, 1024, 128, 128, 128, 0, NN * 128);
    ep_hid<<<dim3(96), blk, 0, stream>>>(arena, rW1, rb1, boxes, hid);

    // decode
    decode_kernel<<<dim3((NN + 255) / 256), blk, 0, stream>>>(hid, rW2, rb2, boxes, out);
}

// Round 4
// 228.637 us; speedup vs baseline: 3.2247x; 1.0842x over previous
//
#include <hip/hip_runtime.h>
#include <math.h>

#define NN 768
#define KK_TOP 20
#define NBR_K 21

typedef __attribute__((ext_vector_type(8))) short bf16x8;
typedef __attribute__((ext_vector_type(4))) float f32x4;
typedef unsigned short ushort_t;
typedef unsigned int uint_t;

__device__ inline ushort_t f2bf(float x) {
    union { float f; uint_t u; } c; c.f = x;
    uint_t r = (c.u + 0x7FFFu + ((c.u >> 16) & 1u)) >> 16;
    return (ushort_t)r;
}
__device__ inline float bf2f(ushort_t u) {
    union { uint_t u; float f; } c; c.u = ((uint_t)u) << 16;
    return c.f;
}

// ============== prep: transpose-cast weights to B^T bf16 + cast feats to bf16 ==============
// blocks 0..63:    Wa   = W1[0:1024]    (1024x256) -> btAB rows 0..255
// blocks 64..127:  Wb   = W1[1024:2048] (1024x256) -> btAB rows 256..511
// blocks 128..383: g1W[:1024] (1024x1024) -> btG
// blocks 384..415: rW1[:1024] (1024x128)  -> btR
// blocks 416..799: cast feats (768x1024) -> featsbf
__global__ __launch_bounds__(256) void prep_kernel(
    const float* __restrict__ W1, const float* __restrict__ g1W,
    const float* __restrict__ rW1, const float* __restrict__ feats,
    ushort_t* __restrict__ btAB, ushort_t* __restrict__ btG,
    ushort_t* __restrict__ btR, ushort_t* __restrict__ featsbf)
{
    int b = blockIdx.x, t = threadIdx.x;
    if (b >= 416) {
        int gid = (b - 416) * 2048 + t * 8;
        float4 v0 = *(const float4*)(feats + gid);
        float4 v1 = *(const float4*)(feats + gid + 4);
        uint4 r;
        r.x = (uint_t)f2bf(v0.x) | ((uint_t)f2bf(v0.y) << 16);
        r.y = (uint_t)f2bf(v0.z) | ((uint_t)f2bf(v0.w) << 16);
        r.z = (uint_t)f2bf(v1.x) | ((uint_t)f2bf(v1.y) << 16);
        r.w = (uint_t)f2bf(v1.z) | ((uint_t)f2bf(v1.w) << 16);
        *(uint4*)(featsbf + gid) = r;
        return;
    }
    const float* in; ushort_t* out; int ldN, tk, tn;
    if (b < 64)       { in = W1;              out = btAB;              ldN = 256;  tn = b & 3;  tk = b >> 2; }
    else if (b < 128) { int i = b - 64;  in = W1 + 1024 * 256; out = btAB + 256 * 1024; ldN = 256;  tn = i & 3;  tk = i >> 2; }
    else if (b < 384) { int i = b - 128; in = g1W;             out = btG;               ldN = 1024; tn = i & 15; tk = i >> 4; }
    else              { int i = b - 384; in = rW1;             out = btR;               ldN = 128;  tn = i & 1;  tk = i >> 1; }

    __shared__ __align__(16) float tile[64][68];
    int k0 = tk * 64, n0 = tn * 64;
#pragma unroll
    for (int it = 0; it < 4; it++) {
        int r = (t >> 4) + it * 16;
        int c = (t & 15) * 4;
        *(float4*)&tile[r][c] = *(const float4*)(in + (size_t)(k0 + r) * ldN + n0 + c);
    }
    __syncthreads();
    int n = t >> 2;
    int kc = (t & 3) * 16;
    uint4 o0, o1;
    uint_t p[8];
#pragma unroll
    for (int h = 0; h < 8; h++) {
        ushort_t lo = f2bf(tile[kc + 2 * h][n]);
        ushort_t hi = f2bf(tile[kc + 2 * h + 1][n]);
        p[h] = (uint_t)lo | ((uint_t)hi << 16);
    }
    o0 = make_uint4(p[0], p[1], p[2], p[3]);
    o1 = make_uint4(p[4], p[5], p[6], p[7]);
    ushort_t* dst = out + (size_t)(n0 + n) * 1024 + k0 + kc;
    *(uint4*)dst = o0;
    *(uint4*)(dst + 8) = o1;
}

// ============== bf16 MFMA GEMM: C(768 x ldc) = A(768x1024 bf16) @ Bt^T, fused epilogues ======
// mode 0: plain store. mode 1: + geom rank-4 (boxes/800 @ Wgeo). mode 2: + geom + bias + relu.
__global__ __launch_bounds__(256) void mfma_gemm(
    const ushort_t* __restrict__ A, const ushort_t* __restrict__ Bt,
    float* __restrict__ C, int ldc, int mode,
    const float* __restrict__ boxes, const float* __restrict__ Wgeo,
    const float* __restrict__ bias)
{
    __shared__ __align__(16) ushort_t As[64][72];
    __shared__ __align__(16) ushort_t Bs[64][72];
    int t = threadIdx.x;
    int m0 = blockIdx.y * 64, n0 = blockIdx.x * 64;
    int lane = t & 63, w = t >> 6;
    int quad = lane >> 4, ci = lane & 15;

    // staging chunks: c in {t, t+256}; r=c>>3 (row), q=c&7 (16B chunk)
    int r0 = t >> 3, q0 = t & 7;
    int r1 = (t + 256) >> 3, q1 = (t + 256) & 7;

    const ushort_t* Abase = A + (size_t)(m0 + r0) * 1024 + q0 * 8;
    const ushort_t* Abase1 = A + (size_t)(m0 + r1) * 1024 + q1 * 8;
    const ushort_t* Bbase = Bt + (size_t)(n0 + r0) * 1024 + q0 * 8;
    const ushort_t* Bbase1 = Bt + (size_t)(n0 + r1) * 1024 + q1 * 8;

    uint4 pa0 = *(const uint4*)(Abase);
    uint4 pa1 = *(const uint4*)(Abase1);
    uint4 pb0 = *(const uint4*)(Bbase);
    uint4 pb1 = *(const uint4*)(Bbase1);

    f32x4 acc[2][2];
    acc[0][0] = (f32x4){0.f, 0.f, 0.f, 0.f};
    acc[0][1] = (f32x4){0.f, 0.f, 0.f, 0.f};
    acc[1][0] = (f32x4){0.f, 0.f, 0.f, 0.f};
    acc[1][1] = (f32x4){0.f, 0.f, 0.f, 0.f};

    int arow = (w & 1) * 32 + ci;
    int brow = (w >> 1) * 32 + ci;

    for (int kt = 0; kt < 16; kt++) {
        *(uint4*)&As[r0][q0 * 8] = pa0;
        *(uint4*)&As[r1][q1 * 8] = pa1;
        *(uint4*)&Bs[r0][q0 * 8] = pb0;
        *(uint4*)&Bs[r1][q1 * 8] = pb1;
        __syncthreads();
        if (kt < 15) {
            int ko = (kt + 1) * 64;
            pa0 = *(const uint4*)(Abase + ko);
            pa1 = *(const uint4*)(Abase1 + ko);
            pb0 = *(const uint4*)(Bbase + ko);
            pb1 = *(const uint4*)(Bbase1 + ko);
        }
#pragma unroll
        for (int s = 0; s < 2; s++) {
            int kb = s * 32 + quad * 8;
            bf16x8 a0 = *(const bf16x8*)&As[arow][kb];
            bf16x8 a1 = *(const bf16x8*)&As[arow + 16][kb];
            bf16x8 b0 = *(const bf16x8*)&Bs[brow][kb];
            bf16x8 b1 = *(const bf16x8*)&Bs[brow + 16][kb];
            acc[0][0] = __builtin_amdgcn_mfma_f32_16x16x32_bf16(a0, b0, acc[0][0], 0, 0, 0);
            acc[0][1] = __builtin_amdgcn_mfma_f32_16x16x32_bf16(a0, b1, acc[0][1], 0, 0, 0);
            acc[1][0] = __builtin_amdgcn_mfma_f32_16x16x32_bf16(a1, b0, acc[1][0], 0, 0, 0);
            acc[1][1] = __builtin_amdgcn_mfma_f32_16x16x32_bf16(a1, b1, acc[1][1], 0, 0, 0);
        }
        __syncthreads();
    }

    const float inv800 = 1.0f / 800.0f;
#pragma unroll
    for (int ni = 0; ni < 2; ni++) {
        int col = n0 + (w >> 1) * 32 + ni * 16 + ci;
        float wg0 = 0.f, wg1 = 0.f, wg2 = 0.f, wg3 = 0.f, bv = 0.f;
        if (mode) {
            wg0 = Wgeo[col]; wg1 = Wgeo[ldc + col];
            wg2 = Wgeo[2 * ldc + col]; wg3 = Wgeo[3 * ldc + col];
            if (mode == 2) bv = bias[col];
        }
#pragma unroll
        for (int mi = 0; mi < 2; mi++) {
            int rbase = m0 + (w & 1) * 32 + mi * 16 + quad * 4;
#pragma unroll
            for (int reg = 0; reg < 4; reg++) {
                int row = rbase + reg;
                float v = acc[mi][ni][reg];
                if (mode) {
                    float4 bx = *(const float4*)(boxes + row * 4);
                    v += (bx.x * wg0 + bx.y * wg1 + bx.z * wg2 + bx.w * wg3) * inv800 + bv;
                    if (mode == 2) v = fmaxf(v, 0.f);
                }
                C[(size_t)row * ldc + col] = v;
            }
        }
    }
}

// ============== rowdot (blocks 0..191) + pack (block 192) ==============
__global__ __launch_bounds__(256) void rowdot_pack_kernel(
    const float* __restrict__ fafb, const float* __restrict__ W1,
    const float* __restrict__ W2, const float* __restrict__ b1,
    float* __restrict__ Arow, float* __restrict__ Brow,
    float4* __restrict__ wgt4, float* __restrict__ w2p, float* __restrict__ consts)
{
    int t = threadIdx.x;
    if (blockIdx.x == 192) {
        const float* Wg = W1 + 2048 * 256;
        float q0 = Wg[t], q1 = Wg[256 + t], q2 = Wg[512 + t], q3 = Wg[768 + t];
        float w2 = W2[t];
        wgt4[t] = make_float4(q0, q1, q2, q3);
        w2p[t] = w2;
        __shared__ float red[256];
        float vals[5] = {q0 * w2, q1 * w2, q2 * w2, q3 * w2, b1[t] * w2};
        for (int d = 0; d < 5; d++) {
            red[t] = vals[d]; __syncthreads();
            for (int s = 128; s > 0; s >>= 1) {
                if (t < s) red[t] += red[t + s];
                __syncthreads();
            }
            if (t == 0) consts[d] = red[0];
            __syncthreads();
        }
        return;
    }
    int gid = blockIdx.x * 256 + t;
    int row = gid >> 6;
    int lane = gid & 63;
    const float4* fr = (const float4*)(fafb + (size_t)row * 512);
    float4 w = ((const float4*)W2)[lane];
    float4 v1 = fr[lane], v2 = fr[64 + lane];
    float s1 = v1.x * w.x + v1.y * w.y + v1.z * w.z + v1.w * w.w;
    float s2 = v2.x * w.x + v2.y * w.y + v2.z * w.z + v2.w * w.w;
#pragma unroll
    for (int off = 32; off > 0; off >>= 1) {
        s1 += __shfl_xor(s1, off);
        s2 += __shfl_xor(s2, off);
    }
    if (lane == 0) { Arow[row] = s1; Brow[row] = s2; }
}

// ============== fused rel: abs-trick + 2x2/thread + scalar uniform coefs ==============
#define REL_ACC(FA0, FA1, FB0, FB1, Q, W)                                           \
    {                                                                               \
        float v;                                                                    \
        v = FA0 + FB0;                                                              \
        v = fmaf(g00.x, Q.x, v); v = fmaf(g00.y, Q.y, v);                           \
        v = fmaf(g00.z, Q.z, v); v = fmaf(g00.w, Q.w, v);                           \
        acc00 = fmaf(fabsf(v), W, acc00);                                           \
        v = FA0 + FB1;                                                              \
        v = fmaf(g01.x, Q.x, v); v = fmaf(g01.y, Q.y, v);                           \
        v = fmaf(g01.z, Q.z, v); v = fmaf(g01.w, Q.w, v);                           \
        acc01 = fmaf(fabsf(v), W, acc01);                                           \
        v = FA1 + FB0;                                                              \
        v = fmaf(g10.x, Q.x, v); v = fmaf(g10.y, Q.y, v);                           \
        v = fmaf(g10.z, Q.z, v); v = fmaf(g10.w, Q.w, v);                           \
        acc10 = fmaf(fabsf(v), W, acc10);                                           \
        v = FA1 + FB1;                                                              \
        v = fmaf(g11.x, Q.x, v); v = fmaf(g11.y, Q.y, v);                           \
        v = fmaf(g11.z, Q.z, v); v = fmaf(g11.w, Q.w, v);                           \
        acc11 = fmaf(fabsf(v), W, acc11);                                           \
    }

__global__ __launch_bounds__(256) void rel_kernel(
    const float* __restrict__ fafb, const float* __restrict__ boxes,
    const float4* __restrict__ wgt4, const float* __restrict__ w2p,
    const float* __restrict__ consts, const float* __restrict__ b1,
    const float* __restrict__ Arow, const float* __restrict__ Brow,
    const float* __restrict__ b2, float* __restrict__ rel)
{
    __shared__ __align__(16) float fas[32][132];
    __shared__ __align__(16) float fbs[32][132];
    int t = threadIdx.x;
    int tx = t & 15, ty = t >> 4;
    int i0 = blockIdx.y * 32, j0 = blockIdx.x * 32;
    int ia = i0 + ty, ib = i0 + ty + 16;
    int ja = j0 + tx, jb = j0 + tx + 16;

    float4 Bi0 = *(const float4*)(boxes + ia * 4);
    float4 Bi1 = *(const float4*)(boxes + ib * 4);
    float4 Bj0 = *(const float4*)(boxes + ja * 4);
    float4 Bj1 = *(const float4*)(boxes + jb * 4);
    float4 g00 = make_float4(fabsf(Bi0.x - Bj0.x), fabsf(Bi0.y - Bj0.y), fabsf(Bi0.z - Bj0.z), fabsf(Bi0.w - Bj0.w));
    float4 g01 = make_float4(fabsf(Bi0.x - Bj1.x), fabsf(Bi0.y - Bj1.y), fabsf(Bi0.z - Bj1.z), fabsf(Bi0.w - Bj1.w));
    float4 g10 = make_float4(fabsf(Bi1.x - Bj0.x), fabsf(Bi1.y - Bj0.y), fabsf(Bi1.z - Bj0.z), fabsf(Bi1.w - Bj0.w));
    float4 g11 = make_float4(fabsf(Bi1.x - Bj1.x), fabsf(Bi1.y - Bj1.y), fabsf(Bi1.z - Bj1.z), fabsf(Bi1.w - Bj1.w));

    float acc00 = 0.f, acc01 = 0.f, acc10 = 0.f, acc11 = 0.f;

    for (int p = 0; p < 2; p++) {
        for (int e = t; e < 1024; e += 256) {
            int r = e >> 5, cq = e & 31;
            float4 bb = *(const float4*)(b1 + p * 128 + cq * 4);
            float4 fv = *(const float4*)(fafb + (size_t)(i0 + r) * 512 + p * 128 + cq * 4);
            float4 gv = *(const float4*)(fafb + (size_t)(j0 + r) * 512 + 256 + p * 128 + cq * 4);
            *(float4*)&fas[r][cq * 4] = make_float4(fv.x + bb.x, fv.y + bb.y, fv.z + bb.z, fv.w + bb.w);
            *(float4*)&fbs[r][cq * 4] = gv;
        }
        __syncthreads();
        const float4* wg = wgt4 + p * 128;
        const float* w2 = w2p + p * 128;
#pragma unroll 8
        for (int hc = 0; hc < 32; hc++) {
            int h4 = hc * 4;
            float4 fa0 = *(const float4*)&fas[ty][h4];
            float4 fa1 = *(const float4*)&fas[ty + 16][h4];
            float4 fb0 = *(const float4*)&fbs[tx][h4];
            float4 fb1 = *(const float4*)&fbs[tx + 16][h4];
            float4 w2v = *(const float4*)(w2 + h4);
            float4 q0 = wg[h4], q1 = wg[h4 + 1], q2 = wg[h4 + 2], q3 = wg[h4 + 3];
            REL_ACC(fa0.x, fa1.x, fb0.x, fb1.x, q0, w2v.x);
            REL_ACC(fa0.y, fa1.y, fb0.y, fb1.y, q1, w2v.y);
            REL_ACC(fa0.z, fa1.z, fb0.z, fb1.z, q2, w2v.z);
            REL_ACC(fa0.w, fa1.w, fb0.w, fb1.w, q3, w2v.w);
        }
        __syncthreads();
    }

    float c0 = consts[0], c1 = consts[1], c2 = consts[2], c3 = consts[3], c4 = consts[4];
    float b2v = b2[0];
    float Ai0 = Arow[ia], Ai1 = Arow[ib];
    float Bja = Brow[ja], Bjb = Brow[jb];

    float lin, r00, r01, r10, r11;
    lin = Ai0 + Bja + g00.x * c0 + g00.y * c1 + g00.z * c2 + g00.w * c3 + c4;
    r00 = 0.5f * (lin + acc00) + b2v;
    lin = Ai0 + Bjb + g01.x * c0 + g01.y * c1 + g01.z * c2 + g01.w * c3 + c4;
    r01 = 0.5f * (lin + acc01) + b2v;
    lin = Ai1 + Bja + g10.x * c0 + g10.y * c1 + g10.z * c2 + g10.w * c3 + c4;
    r10 = 0.5f * (lin + acc10) + b2v;
    lin = Ai1 + Bjb + g11.x * c0 + g11.y * c1 + g11.z * c2 + g11.w * c3 + c4;
    r11 = 0.5f * (lin + acc11) + b2v;
    rel[(size_t)ia * NN + ja] = (ia == ja) ? -1e9f : r00;
    rel[(size_t)ia * NN + jb] = (ia == jb) ? -1e9f : r01;
    rel[(size_t)ib * NN + ja] = (ib == ja) ? -1e9f : r10;
    rel[(size_t)ib * NN + jb] = (ib == jb) ? -1e9f : r11;
}

// ============== top-20 per row: one wave per row ==============
__global__ __launch_bounds__(256) void topk_kernel(const float* __restrict__ rel, int* __restrict__ nbr)
{
    int gid = blockIdx.x * 256 + threadIdx.x;
    int row = gid >> 6;
    int lane = gid & 63;
    const float* rp = rel + (size_t)row * NN;
    float v[12];
#pragma unroll
    for (int q = 0; q < 12; q++) v[q] = rp[q * 64 + lane];
    for (int kk = 0; kk < KK_TOP; kk++) {
        float best = v[0]; int bq = 0;
#pragma unroll
        for (int q = 1; q < 12; q++) {
            if (v[q] > best) { best = v[q]; bq = q; }
        }
        int bidx = bq * 64 + lane;
#pragma unroll
        for (int off = 32; off > 0; off >>= 1) {
            float ov = __shfl_xor(best, off);
            int oi = __shfl_xor(bidx, off);
            if (ov > best || (ov == best && oi < bidx)) { best = ov; bidx = oi; }
        }
        if (lane == 0) nbr[row * NBR_K + kk] = bidx;
        int bl = bidx & 63, bq2 = bidx >> 6;
        if (lane == bl) {
#pragma unroll
            for (int q = 0; q < 12; q++)
                if (q == bq2) v[q] = -INFINITY;
        }
    }
    if (lane == 0) nbr[row * NBR_K + KK_TOP] = row;
}

// ============== GAT1 attention coefficients: one wave per (n,h) ==============
__global__ __launch_bounds__(256) void attn_coef_kernel(
    const float* __restrict__ xp, const float* __restrict__ g1as, const float* __restrict__ g1ad,
    float* __restrict__ asrc, float* __restrict__ adst)
{
    int gid = blockIdx.x * 256 + threadIdx.x;
    int wv = gid >> 6;
    int lane = gid & 63;
    int n = wv >> 2, h = wv & 3;
    const float4* xr = (const float4*)(xp + (size_t)n * 1024 + h * 256);
    const float4* wsrc = (const float4*)(g1as + h * 256);
    const float4* wdst = (const float4*)(g1ad + h * 256);
    float4 x4 = xr[lane], a4 = wsrc[lane], b4 = wdst[lane];
    float s1 = x4.x * a4.x + x4.y * a4.y + x4.z * a4.z + x4.w * a4.w;
    float s2 = x4.x * b4.x + x4.y * b4.y + x4.z * b4.z + x4.w * b4.w;
#pragma unroll
    for (int off = 32; off > 0; off >>= 1) {
        s1 += __shfl_xor(s1, off);
        s2 += __shfl_xor(s2, off);
    }
    if (lane == 0) { asrc[wv] = s1; adst[wv] = s2; }
}

// ============== GAT1 aggregate -> h1 (bf16) ==============
__global__ __launch_bounds__(256) void gat1_kernel(
    const float* __restrict__ xp, const float* __restrict__ asrc, const float* __restrict__ adst,
    const int* __restrict__ nbr, const float* __restrict__ g1b, ushort_t* __restrict__ h1bf)
{
    int n = blockIdx.x; int t = threadIdx.x;
    __shared__ int nb[NBR_K];
    __shared__ float alpha[NBR_K][4];
    if (t < NBR_K) nb[t] = nbr[n * NBR_K + t];
    __syncthreads();
    if (t < NBR_K * 4) {
        int k = t % NBR_K, h = t / NBR_K;
        float e = asrc[nb[k] * 4 + h] + adst[n * 4 + h];
        e = (e > 0.f) ? e : 0.2f * e;
        alpha[k][h] = e;
    }
    __syncthreads();
    if (t < 4) {
        float m = -INFINITY;
        for (int k = 0; k < NBR_K; k++) m = fmaxf(m, alpha[k][t]);
        float s = 0.f;
        for (int k = 0; k < NBR_K; k++) { float ex = expf(alpha[k][t] - m); alpha[k][t] = ex; s += ex; }
        float inv = 1.f / s;
        for (int k = 0; k < NBR_K; k++) alpha[k][t] *= inv;
    }
    __syncthreads();
#pragma unroll
    for (int q = 0; q < 4; q++) {
        int c = q * 256 + t;
        int h = c >> 8;
        float acc = 0.f;
        for (int k = 0; k < NBR_K; k++) acc += alpha[k][h] * xp[(size_t)nb[k] * 1024 + c];
        h1bf[(size_t)n * 1024 + c] = f2bf(fmaxf(acc + g1b[c], 0.f));
    }
}

// ============== GAT2 part A (reads bf16 h1) ==============
__global__ __launch_bounds__(256) void gat2a_kernel(
    const ushort_t* __restrict__ h1bf, const float* __restrict__ g2W,
    const float* __restrict__ g2as, const float* __restrict__ g2ad,
    float* __restrict__ xp2, float* __restrict__ aux2)
{
    int gid = blockIdx.x * blockDim.x + threadIdx.x;
    int wid = gid >> 6;
    int lane = threadIdx.x & 63;
    if (wid >= NN) return;
    float s0 = 0.f, s1 = 0.f;
#pragma unroll
    for (int it = 0; it < 4; it++) {
        int k = it * 256 + lane * 4;
        uint2 p = *(const uint2*)(h1bf + (size_t)wid * 1024 + k);
        float v0 = bf2f((ushort_t)(p.x & 0xFFFF));
        float v1 = bf2f((ushort_t)(p.x >> 16));
        float v2 = bf2f((ushort_t)(p.y & 0xFFFF));
        float v3 = bf2f((ushort_t)(p.y >> 16));
        float4 w0 = *(const float4*)(g2W + k * 2);
        float4 w1 = *(const float4*)(g2W + k * 2 + 4);
        s0 += v0 * w0.x + v1 * w0.z + v2 * w1.x + v3 * w1.z;
        s1 += v0 * w0.y + v1 * w0.w + v2 * w1.y + v3 * w1.w;
    }
#pragma unroll
    for (int off = 32; off > 0; off >>= 1) { s0 += __shfl_down(s0, off); s1 += __shfl_down(s1, off); }
    if (lane == 0) {
        xp2[wid * 2 + 0] = s0; xp2[wid * 2 + 1] = s1;
        aux2[wid * 2 + 0] = s0 * g2as[0] + s1 * g2as[1];
        aux2[wid * 2 + 1] = s0 * g2ad[0] + s1 * g2ad[1];
    }
}

// ============== GAT2 part B ==============
__global__ void gat2b_kernel(const float* __restrict__ xp2, const float* __restrict__ aux2,
                             const int* __restrict__ nbr, const float* __restrict__ g2b,
                             float* __restrict__ out)
{
    int n = blockIdx.x * 256 + threadIdx.x;
    if (n >= NN) return;
    float adst = aux2[n * 2 + 1];
    int nb[NBR_K];
    float e[NBR_K];
    float m = -INFINITY;
    for (int k = 0; k < NBR_K; k++) {
        nb[k] = nbr[n * NBR_K + k];
        float v = aux2[nb[k] * 2 + 0] + adst;
        v = (v > 0.f) ? v : 0.2f * v;
        e[k] = v; m = fmaxf(m, v);
    }
    float s = 0.f;
    for (int k = 0; k < NBR_K; k++) { e[k] = expf(e[k] - m); s += e[k]; }
    float inv = 1.f / s;
    float o0 = 0.f, o1 = 0.f;
    for (int k = 0; k < NBR_K; k++) {
        float a = e[k] * inv;
        o0 += a * xp2[nb[k] * 2 + 0];
        o1 += a * xp2[nb[k] * 2 + 1];
    }
    out[n * 6 + 0] = o0 + g2b[0];
    out[n * 6 + 1] = o1 + g2b[1];
}

// ============== decode ==============
__global__ void decode_kernel(const float* __restrict__ hid, const float* __restrict__ rW2,
                              const float* __restrict__ rb2, const float* __restrict__ boxes,
                              float* __restrict__ out)
{
    int n = blockIdx.x * 256 + threadIdx.x;
    if (n >= NN) return;
    float d0 = 0.f, d1 = 0.f, d2 = 0.f, d3 = 0.f;
    for (int k = 0; k < 128; k++) {
        float v = hid[n * 128 + k];
        d0 += v * rW2[k * 4 + 0];
        d1 += v * rW2[k * 4 + 1];
        d2 += v * rW2[k * 4 + 2];
        d3 += v * rW2[k * 4 + 3];
    }
    d0 += rb2[0]; d1 += rb2[1]; d2 += rb2[2]; d3 += rb2[3];
    float x0 = boxes[n * 4 + 0], y0 = boxes[n * 4 + 1], x1 = boxes[n * 4 + 2], y1 = boxes[n * 4 + 3];
    float pw = x1 - x0, ph = y1 - y0;
    float pcx = x0 + 0.5f * pw, pcy = y0 + 0.5f * ph;
    float gcx = d0 * pw + pcx, gcy = d1 * ph + pcy;
    float gw = expf(d2) * pw, gh = expf(d3) * ph;
    out[n * 6 + 2] = gcx - 0.5f * gw;
    out[n * 6 + 3] = gcy - 0.5f * gh;
    out[n * 6 + 4] = gcx + 0.5f * gw;
    out[n * 6 + 5] = gcy + 0.5f * gh;
}

extern "C" void kernel_launch(void* const* d_in, const int* in_sizes, int n_in,
                              void* d_out, int out_size, void* d_ws, size_t ws_size,
                              hipStream_t stream)
{
    const float* feats = (const float*)d_in[0];
    const float* boxes = (const float*)d_in[1];
    const float* W1    = (const float*)d_in[2];
    const float* b1    = (const float*)d_in[3];
    const float* W2    = (const float*)d_in[4];
    const float* b2    = (const float*)d_in[5];
    const float* g1W   = (const float*)d_in[6];
    const float* g1as  = (const float*)d_in[7];
    const float* g1ad  = (const float*)d_in[8];
    const float* g1b   = (const float*)d_in[9];
    const float* g2W   = (const float*)d_in[10];
    const float* g2as  = (const float*)d_in[11];
    const float* g2ad  = (const float*)d_in[12];
    const float* g2b   = (const float*)d_in[13];
    const float* rW1   = (const float*)d_in[14];
    const float* rb1   = (const float*)d_in[15];
    const float* rW2   = (const float*)d_in[16];
    const float* rb2   = (const float*)d_in[17];
    float* out = (float*)d_out;

    // workspace layout
    float* ws    = (float*)d_ws;
    float* fafb  = ws;                    // 768*512
    float* xp    = fafb + 393216;         // 768*1024
    float* rel   = xp + 786432;           // 768*768
    float* hid   = rel + 589824;          // 768*128
    float* Arow  = hid + 98304;           // 768
    float* Brow  = Arow + 768;            // 768
    float* asrc  = Brow + 768;            // 3072
    float* adst  = asrc + 3072;           // 3072
    float* xp2   = adst + 3072;           // 1536
    float* aux2  = xp2 + 1536;            // 1536
    float4* wgt4 = (float4*)(aux2 + 1536);// 256 float4
    float* w2p   = (float*)(wgt4 + 256);  // 256
    float* consts= w2p + 256;             // 8
    int*   nbr   = (int*)(consts + 8);    // 768*21 = 16128
    ushort_t* featsbf = (ushort_t*)(nbr + 16128);  // 768*1024
    ushort_t* btAB    = featsbf + 786432;          // 512*1024
    ushort_t* btG     = btAB + 524288;             // 1024*1024
    ushort_t* btR     = btG + 1048576;             // 128*1024
    ushort_t* h1bf    = btR + 131072;              // 768*1024

    dim3 blk(256);

    // 1. prep: weight transposes + feats cast
    prep_kernel<<<dim3(800), blk, 0, stream>>>(W1, g1W, rW1, feats, btAB, btG, btR, featsbf);

    // 2. G1: fafb = feats @ [Wa|Wb]  (bf16 MFMA)
    mfma_gemm<<<dim3(8, 12), blk, 0, stream>>>(featsbf, btAB, fafb, 512, 0, nullptr, nullptr, nullptr);

    // 3. rowdot + pack
    rowdot_pack_kernel<<<dim3(193), blk, 0, stream>>>(fafb, W1, W2, b1, Arow, Brow, wgt4, w2p, consts);

    // 4. G2: xp = feats @ g1W[:1024] + geom rank-4  (bf16 MFMA, fused epilogue)
    mfma_gemm<<<dim3(16, 12), blk, 0, stream>>>(featsbf, btG, xp, 1024, 1, boxes, g1W + (size_t)1024 * 1024, nullptr);

    // 5. rel + 6. topk
    rel_kernel<<<dim3(NN / 32, NN / 32), blk, 0, stream>>>(
        fafb, boxes, wgt4, w2p, consts, b1, Arow, Brow, b2, rel);
    topk_kernel<<<dim3(192), blk, 0, stream>>>(rel, nbr);

    // 7-8. GAT1
    attn_coef_kernel<<<dim3(768), blk, 0, stream>>>(xp, g1as, g1ad, asrc, adst);
    gat1_kernel<<<dim3(NN), blk, 0, stream>>>(xp, asrc, adst, nbr, g1b, h1bf);

    // 9-10. GAT2
    gat2a_kernel<<<dim3(NN * 64 / 256), blk, 0, stream>>>(h1bf, g2W, g2as, g2ad, xp2, aux2);
    gat2b_kernel<<<dim3((NN + 255) / 256), blk, 0, stream>>>(xp2, aux2, nbr, g2b, out);

    // 11. G3: hid = relu(h1 @ rW1[:1024] + geom + rb1)  (bf16 MFMA, fused epilogue)
    mfma_gemm<<<dim3(2, 12), blk, 0, stream>>>(h1bf, btR, hid, 128, 2, boxes, rW1 + (size_t)1024 * 128, rb1);

    // 12. decode
    decode_kernel<<<dim3((NN + 255) / 256), blk, 0, stream>>>(hid, rW2, rb2, boxes, out);
}